// Round 4
// baseline (941.307 us; speedup 1.0000x reference)
//
#include <hip/hip_runtime.h>
#include <stdint.h>
#include <math.h>

// ---------------------------------------------------------------------------
// EncoderLayer. I/O dtype: fp32 (per reference setup_inputs), mask int32.
// Internal compute: bf16 MFMA with fp32 accumulate.
// cvt x -> bf16; convert+transpose weights -> bf16 [N,K]; QKV GEMMs ->
// flash attn -> Wo GEMM -> LN+res+LN -> FFN quarters (GELU) -> res+LN -> fp32 out
// ---------------------------------------------------------------------------

typedef uint16_t u16;
typedef __attribute__((ext_vector_type(8))) short short8;   // 8 x bf16
typedef __attribute__((ext_vector_type(4))) float f32x4;

#define S_LEN 2048
#define DM 1024

__device__ __forceinline__ float bf2f(u16 h) {
  union { uint32_t u; float f; } x;
  x.u = ((uint32_t)h) << 16;
  return x.f;
}
__device__ __forceinline__ u16 f2bf(float f) {
  union { float f; uint32_t u; } x;
  x.f = f;
  uint32_t r = (x.u + 0x7fffu + ((x.u >> 16) & 1u)) >> 16;  // RNE
  return (u16)r;
}

union U8 { uint4 u; u16 s[8]; };
union U4 { uint2 u; u16 s[4]; };

// ---------------------------------------------------------------------------
// fp32 -> bf16 elementwise. n multiple of 1024. grid n/1024, 256 thr.
// ---------------------------------------------------------------------------
__global__ __launch_bounds__(256) void cvt_k(const float* __restrict__ in,
                                             u16* __restrict__ out, int n) {
  int i = (blockIdx.x * 256 + threadIdx.x) * 4;
  if (i >= n) return;
  float4 v = *(const float4*)(in + i);
  U4 o;
  o.s[0] = f2bf(v.x); o.s[1] = f2bf(v.y); o.s[2] = f2bf(v.z); o.s[3] = f2bf(v.w);
  *(uint2*)(out + i) = o.u;
}

// ---------------------------------------------------------------------------
// Weight convert+transpose: fp32 in [R,C] -> bf16 out [C,R]. grid(C/64,R/64)
// ---------------------------------------------------------------------------
__global__ __launch_bounds__(256) void transpose_cvt_k(const float* __restrict__ in,
                                                       u16* __restrict__ out,
                                                       int R, int C) {
  __shared__ u16 tile[64][72];
  int c0 = blockIdx.x * 64, r0 = blockIdx.y * 64;
  int t = threadIdx.x;
  int r = t & 63, seg = t >> 6;  // 16-col segment per thread
  const float* src = in + (size_t)(r0 + r) * C + c0 + seg * 16;
#pragma unroll
  for (int q = 0; q < 4; q++) {
    float4 v = *(const float4*)(src + q * 4);
    tile[r][seg * 16 + q * 4 + 0] = f2bf(v.x);
    tile[r][seg * 16 + q * 4 + 1] = f2bf(v.y);
    tile[r][seg * 16 + q * 4 + 2] = f2bf(v.z);
    tile[r][seg * 16 + q * 4 + 3] = f2bf(v.w);
  }
  __syncthreads();
  U8 v0, v1;
#pragma unroll
  for (int i = 0; i < 8; i++) v0.s[i] = tile[seg * 16 + i][r];
#pragma unroll
  for (int i = 0; i < 8; i++) v1.s[i] = tile[seg * 16 + 8 + i][r];
  u16* dst = out + (size_t)(c0 + r) * R + r0 + seg * 16;
  *(uint4*)dst = v0.u;
  *(uint4*)(dst + 8) = v1.u;
}

// ---------------------------------------------------------------------------
// bf16 GEMM: C[M,N] = A[M,K] @ Bt[N,K]^T, 128x128 tile, BK=32, 4 waves.
// bias fp32. EPI: 0=+bias ; 1=+bias+bias2 ; 2=+bias then exact GELU
// ---------------------------------------------------------------------------
template <int EPI>
__global__ __launch_bounds__(256) void gemm_bt(const u16* __restrict__ A,
                                               const u16* __restrict__ Bt,
                                               u16* __restrict__ C,
                                               const float* __restrict__ bias,
                                               const float* __restrict__ bias2,
                                               int M, int N, int K) {
  __shared__ u16 As[128 * 32];
  __shared__ u16 Bs[128 * 32];
  int t = threadIdx.x;
  int wid = t >> 6, lane = t & 63;
  int g = lane >> 4, li = lane & 15;
  int bx = blockIdx.x, by = blockIdx.y;
  int wr = (wid >> 1) * 64, wc = (wid & 1) * 64;

  const u16* a0 = A + (size_t)(by * 128 + wid * 32 + (lane >> 2)) * K + (lane & 3) * 8;
  const u16* b0 = Bt + (size_t)(bx * 128 + wid * 32 + (lane >> 2)) * K + (lane & 3) * 8;
  u16* lA = &As[wid * 1024 + lane * 8];
  u16* lB = &Bs[wid * 1024 + lane * 8];

  f32x4 acc[4][4];
#pragma unroll
  for (int i = 0; i < 4; i++)
#pragma unroll
    for (int j = 0; j < 4; j++) acc[i][j] = (f32x4){0.f, 0.f, 0.f, 0.f};

  for (int k0 = 0; k0 < K; k0 += 32) {
    uint4 va0 = *(const uint4*)(a0 + k0);
    uint4 va1 = *(const uint4*)(a0 + (size_t)16 * K + k0);
    uint4 vb0 = *(const uint4*)(b0 + k0);
    uint4 vb1 = *(const uint4*)(b0 + (size_t)16 * K + k0);
    *(uint4*)lA = va0;
    *(uint4*)(lA + 512) = va1;
    *(uint4*)lB = vb0;
    *(uint4*)(lB + 512) = vb1;
    __syncthreads();
    short8 af[4], bfv[4];
#pragma unroll
    for (int i = 0; i < 4; i++)
      af[i] = *(const short8*)&As[(wr + i * 16 + li) * 32 + g * 8];
#pragma unroll
    for (int i = 0; i < 4; i++)
      bfv[i] = *(const short8*)&Bs[(wc + i * 16 + li) * 32 + g * 8];
#pragma unroll
    for (int mi = 0; mi < 4; mi++)
#pragma unroll
      for (int ni = 0; ni < 4; ni++)
        acc[mi][ni] = __builtin_amdgcn_mfma_f32_16x16x32_bf16(
            af[mi], bfv[ni], acc[mi][ni], 0, 0, 0);
    __syncthreads();
  }

  // C/D layout: col = lane&15, row = (lane>>4)*4 + reg
#pragma unroll
  for (int ni = 0; ni < 4; ni++) {
    int col = bx * 128 + wc + ni * 16 + li;
    float bv = bias[col];
    if (EPI == 1) bv += bias2[col];
#pragma unroll
    for (int mi = 0; mi < 4; mi++) {
#pragma unroll
      for (int r = 0; r < 4; r++) {
        int row = by * 128 + wr + mi * 16 + g * 4 + r;
        float v = acc[mi][ni][r] + bv;
        if (EPI == 2) v = 0.5f * v * (1.0f + erff(v * 0.70710678118654752f));
        C[(size_t)row * N + col] = f2bf(v);
      }
    }
  }
}

// ---------------------------------------------------------------------------
// Flash attention. grid = 1024 (b,h,64-row q-tile), 256 thr (4 waves).
// ---------------------------------------------------------------------------
__global__ __launch_bounds__(256) void attn_k(const u16* __restrict__ Q,
                                              const u16* __restrict__ Kp,
                                              const u16* __restrict__ Vp,
                                              u16* __restrict__ CTX,
                                              const int* __restrict__ mask,
                                              const float* __restrict__ gateW,
                                              const float* __restrict__ gateb,
                                              const float* __restrict__ temp) {
  __shared__ u16 Qs[64][72];
  __shared__ u16 Ks[64][72];
  __shared__ u16 Vt[64][72];      // V^T: [d][kpos]
  __shared__ u16 Ps[4][16][72];   // per-wave P bounce (C-layout -> A-layout)
  __shared__ float gate_s[64];

  int blk = blockIdx.x;
  int qt = blk & 31, h = (blk >> 5) & 15, b = blk >> 9;
  int t = threadIdx.x, wid = t >> 6, lane = t & 63;
  int g = lane >> 4, li = lane & 15;
  int sq0 = qt * 64;

  const u16* Qb = Q + ((size_t)b * S_LEN) * DM + h * 64;
  const u16* Kb = Kp + ((size_t)b * S_LEN) * DM + h * 64;
  const u16* Vb = Vp + ((size_t)b * S_LEN) * DM + h * 64;

  {
    int r = t >> 2, cs = (t & 3) * 16;
    const u16* src = Qb + (size_t)(sq0 + r) * DM + cs;
    *(uint4*)&Qs[r][cs] = *(const uint4*)src;
    *(uint4*)&Qs[r][cs + 8] = *(const uint4*)(src + 8);
  }
  __syncthreads();
  if (t < 64) {  // per-q-row gate (q already includes bq + time_weights)
    float acc = gateb[0];
#pragma unroll
    for (int d = 0; d < 64; d++) acc += bf2f(Qs[t][d]) * gateW[d];
    gate_s[t] = 1.f / (1.f + __expf(-acc));
  }
  __syncthreads();

  float invt = 1.f / temp[0];
  short8 qf0 = *(const short8*)&Qs[wid * 16 + li][g * 8];
  short8 qf1 = *(const short8*)&Qs[wid * 16 + li][32 + g * 8];
  float gq[4];
  int sq[4];
#pragma unroll
  for (int r = 0; r < 4; r++) {
    gq[r] = gate_s[wid * 16 + g * 4 + r];
    sq[r] = sq0 + wid * 16 + g * 4 + r;
  }

  float m_i[4], l_i[4];
  f32x4 o[4];
#pragma unroll
  for (int r = 0; r < 4; r++) { m_i[r] = -1e30f; l_i[r] = 0.f; }
#pragma unroll
  for (int n = 0; n < 4; n++) o[n] = (f32x4){0.f, 0.f, 0.f, 0.f};

  for (int kt = 0; kt < 32; kt++) {
    __syncthreads();  // Ks/Vt overwrite vs previous iter reads
    {
      int r = t >> 2, cs = (t & 3) * 16;
      const u16* srcK = Kb + (size_t)(kt * 64 + r) * DM + cs;
      *(uint4*)&Ks[r][cs] = *(const uint4*)srcK;
      *(uint4*)&Ks[r][cs + 8] = *(const uint4*)(srcK + 8);
      const u16* srcV = Vb + (size_t)(kt * 64 + r) * DM + cs;
      U8 v0, v1;
      v0.u = *(const uint4*)srcV;
      v1.u = *(const uint4*)(srcV + 8);
#pragma unroll
      for (int i = 0; i < 8; i++) Vt[cs + i][r] = v0.s[i];
#pragma unroll
      for (int i = 0; i < 8; i++) Vt[cs + 8 + i][r] = v1.s[i];
    }
    __syncthreads();

    // S = Q K^T
    f32x4 sc[4];
#pragma unroll
    for (int ni = 0; ni < 4; ni++) {
      sc[ni] = (f32x4){0.f, 0.f, 0.f, 0.f};
      short8 kf0 = *(const short8*)&Ks[ni * 16 + li][g * 8];
      short8 kf1 = *(const short8*)&Ks[ni * 16 + li][32 + g * 8];
      sc[ni] = __builtin_amdgcn_mfma_f32_16x16x32_bf16(qf0, kf0, sc[ni], 0, 0, 0);
      sc[ni] = __builtin_amdgcn_mfma_f32_16x16x32_bf16(qf1, kf1, sc[ni], 0, 0, 0);
    }

    float sval[4][4];
    float rmax[4] = {-1e30f, -1e30f, -1e30f, -1e30f};
#pragma unroll
    for (int ni = 0; ni < 4; ni++) {
      int sk = kt * 64 + ni * 16 + li;
#pragma unroll
      for (int r = 0; r < 4; r++) {
        float s = sc[ni][r];
        int mv = mask[(size_t)sq[r] * S_LEN + sk];
        s = (mv == 0) ? -1e9f : s * invt;  // exact reference order
        s *= gq[r];
        sval[ni][r] = s;
        rmax[r] = fmaxf(rmax[r], s);
      }
    }
#pragma unroll
    for (int off = 1; off < 16; off <<= 1)
#pragma unroll
      for (int r = 0; r < 4; r++)
        rmax[r] = fmaxf(rmax[r], __shfl_xor(rmax[r], off, 64));

    float alpha[4], psum[4];
#pragma unroll
    for (int r = 0; r < 4; r++) {
      float mnew = fmaxf(m_i[r], rmax[r]);
      alpha[r] = __expf(m_i[r] - mnew);
      m_i[r] = mnew;
      psum[r] = 0.f;
    }
#pragma unroll
    for (int ni = 0; ni < 4; ni++)
#pragma unroll
      for (int r = 0; r < 4; r++) {
        float p = __expf(sval[ni][r] - m_i[r]);
        psum[r] += p;
        Ps[wid][g * 4 + r][ni * 16 + li] = f2bf(p);
      }
#pragma unroll
    for (int off = 1; off < 16; off <<= 1)
#pragma unroll
      for (int r = 0; r < 4; r++) psum[r] += __shfl_xor(psum[r], off, 64);
#pragma unroll
    for (int r = 0; r < 4; r++) l_i[r] = l_i[r] * alpha[r] + psum[r];
#pragma unroll
    for (int n = 0; n < 4; n++)
#pragma unroll
      for (int r = 0; r < 4; r++) o[n][r] *= alpha[r];

    __syncthreads();  // fence Ps stores before short8 re-read

    // O += P V
    short8 pf0 = *(const short8*)&Ps[wid][li][g * 8];
    short8 pf1 = *(const short8*)&Ps[wid][li][32 + g * 8];
#pragma unroll
    for (int ni = 0; ni < 4; ni++) {
      short8 vf0 = *(const short8*)&Vt[ni * 16 + li][g * 8];
      short8 vf1 = *(const short8*)&Vt[ni * 16 + li][32 + g * 8];
      o[ni] = __builtin_amdgcn_mfma_f32_16x16x32_bf16(pf0, vf0, o[ni], 0, 0, 0);
      o[ni] = __builtin_amdgcn_mfma_f32_16x16x32_bf16(pf1, vf1, o[ni], 0, 0, 0);
    }
  }

#pragma unroll
  for (int r = 0; r < 4; r++) l_i[r] = 1.f / l_i[r];
#pragma unroll
  for (int ni = 0; ni < 4; ni++) {
    int col = h * 64 + ni * 16 + li;
#pragma unroll
    for (int r = 0; r < 4; r++) {
      size_t row = (size_t)b * S_LEN + sq[r];
      CTX[row * DM + col] = f2bf(o[ni][r] * l_i[r]);
    }
  }
}

// ---------------------------------------------------------------------------
// LayerNorm kernels. One block per row (1024 cols, 4/thread). Params fp32.
// ---------------------------------------------------------------------------
__device__ __forceinline__ void block_sum2(float& a, float& b, float* red, int t) {
#pragma unroll
  for (int off = 32; off > 0; off >>= 1) {
    a += __shfl_xor(a, off, 64);
    b += __shfl_xor(b, off, 64);
  }
  __syncthreads();  // guards red[] reuse between calls
  if ((t & 63) == 0) {
    red[(t >> 6) * 2] = a;
    red[(t >> 6) * 2 + 1] = b;
  }
  __syncthreads();
  a = red[0] + red[2] + red[4] + red[6];
  b = red[1] + red[3] + red[5] + red[7];
}

// x1 = LN(x + LN(po)*g1+b1, g2, b2); po bf16, x fp32, x1 bf16
__global__ __launch_bounds__(256) void ln1_k(const u16* __restrict__ po,
                                             const float* __restrict__ x,
                                             const float* __restrict__ g1,
                                             const float* __restrict__ b1,
                                             const float* __restrict__ g2,
                                             const float* __restrict__ b2,
                                             u16* __restrict__ x1) {
  __shared__ float red[8];
  int row = blockIdx.x, t = threadIdx.x;
  size_t base = (size_t)row * 1024 + t * 4;
  U4 pv; pv.u = *(const uint2*)(po + base);
  float v[4];
#pragma unroll
  for (int i = 0; i < 4; i++) v[i] = bf2f(pv.s[i]);
  float s1 = v[0] + v[1] + v[2] + v[3];
  float s2 = v[0]*v[0] + v[1]*v[1] + v[2]*v[2] + v[3]*v[3];
  block_sum2(s1, s2, red, t);
  float mu = s1 * (1.f / 1024.f);
  float rs = rsqrtf(s2 * (1.f / 1024.f) - mu * mu + 1e-5f);
  float4 xv = *(const float4*)(x + base);
  float4 g1v = *(const float4*)(g1 + t * 4);
  float4 b1v = *(const float4*)(b1 + t * 4);
  float w[4];
  w[0] = xv.x + ((v[0] - mu) * rs * g1v.x + b1v.x);
  w[1] = xv.y + ((v[1] - mu) * rs * g1v.y + b1v.y);
  w[2] = xv.z + ((v[2] - mu) * rs * g1v.z + b1v.z);
  w[3] = xv.w + ((v[3] - mu) * rs * g1v.w + b1v.w);
  s1 = w[0] + w[1] + w[2] + w[3];
  s2 = w[0]*w[0] + w[1]*w[1] + w[2]*w[2] + w[3]*w[3];
  block_sum2(s1, s2, red, t);
  mu = s1 * (1.f / 1024.f);
  rs = rsqrtf(s2 * (1.f / 1024.f) - mu * mu + 1e-5f);
  float4 g2v = *(const float4*)(g2 + t * 4);
  float4 b2v = *(const float4*)(b2 + t * 4);
  U4 ov;
  ov.s[0] = f2bf((w[0] - mu) * rs * g2v.x + b2v.x);
  ov.s[1] = f2bf((w[1] - mu) * rs * g2v.y + b2v.y);
  ov.s[2] = f2bf((w[2] - mu) * rs * g2v.z + b2v.z);
  ov.s[3] = f2bf((w[3] - mu) * rs * g2v.w + b2v.w);
  *(uint2*)(x1 + base) = ov.u;
}

// out = LN(x1 + y, g, b); y,x1 bf16; out fp32
__global__ __launch_bounds__(256) void ln2_k(const u16* __restrict__ y,
                                             const u16* __restrict__ x1,
                                             const float* __restrict__ g,
                                             const float* __restrict__ b,
                                             float* __restrict__ out) {
  __shared__ float red[8];
  int row = blockIdx.x, t = threadIdx.x;
  size_t base = (size_t)row * 1024 + t * 4;
  U4 yv; yv.u = *(const uint2*)(y + base);
  U4 xv; xv.u = *(const uint2*)(x1 + base);
  float w[4];
#pragma unroll
  for (int i = 0; i < 4; i++) w[i] = bf2f(yv.s[i]) + bf2f(xv.s[i]);
  float s1 = w[0] + w[1] + w[2] + w[3];
  float s2 = w[0]*w[0] + w[1]*w[1] + w[2]*w[2] + w[3]*w[3];
  block_sum2(s1, s2, red, t);
  float mu = s1 * (1.f / 1024.f);
  float rs = rsqrtf(s2 * (1.f / 1024.f) - mu * mu + 1e-5f);
  float4 gv = *(const float4*)(g + t * 4);
  float4 bv = *(const float4*)(b + t * 4);
  float4 ov;
  ov.x = (w[0] - mu) * rs * gv.x + bv.x;
  ov.y = (w[1] - mu) * rs * gv.y + bv.y;
  ov.z = (w[2] - mu) * rs * gv.z + bv.z;
  ov.w = (w[3] - mu) * rs * gv.w + bv.w;
  *(float4*)(out + base) = ov;
}

// ---------------------------------------------------------------------------
extern "C" void kernel_launch(void* const* d_in, const int* in_sizes, int n_in,
                              void* d_out, int out_size, void* d_ws, size_t ws_size,
                              hipStream_t stream) {
  (void)in_sizes; (void)n_in; (void)out_size; (void)ws_size;
  const float* x    = (const float*)d_in[0];
  const int*   mask = (const int*)d_in[1];
  const float* Wq = (const float*)d_in[2];  const float* bq = (const float*)d_in[3];
  const float* Wk = (const float*)d_in[4];  const float* bk = (const float*)d_in[5];
  const float* Wv = (const float*)d_in[6];  const float* bv = (const float*)d_in[7];
  const float* Wo = (const float*)d_in[8];  const float* bo = (const float*)d_in[9];
  const float* temp = (const float*)d_in[10];
  const float* tw   = (const float*)d_in[11];
  const float* gW   = (const float*)d_in[12]; const float* gb  = (const float*)d_in[13];
  const float* lag  = (const float*)d_in[14]; const float* lab = (const float*)d_in[15];
  const float* f1W  = (const float*)d_in[16]; const float* f1b = (const float*)d_in[17];
  const float* f2W  = (const float*)d_in[18]; const float* f2b = (const float*)d_in[19];
  const float* n1g  = (const float*)d_in[20]; const float* n1b = (const float*)d_in[21];
  const float* n2g  = (const float*)d_in[22]; const float* n2b = (const float*)d_in[23];
  float* out = (float*)d_out;

  // ws: 5 bf16 slots x 8 MiB = 40 MiB. d_out (16 MiB fp32) doubles as scratch:
  // CTX (bf16, first 8 MiB) until Wo GEMM, then f2W^T (bf16) until ln2.
  u16* ws = (u16*)d_ws;
  const size_t MB4 = (size_t)4096 * 1024;   // elements per 8 MiB bf16 slot
  u16* WT  = ws;               // slot 0: WqT/WkT/WvT/WoT then f1WT
  u16* Qb  = ws + 1 * MB4;     // slot 1: Q -> PO -> Y
  u16* Kb  = ws + 2 * MB4;     // slot 2: K -> X1
  u16* Vb  = ws + 3 * MB4;     // slot 3: V -> H quarter (1024x4096)
  u16* xb  = ws + 4 * MB4;     // slot 4: x in bf16
  u16* CT  = (u16*)d_out;      // d_out scratch: ctx (bf16)
  u16* WT2 = (u16*)d_out;      // d_out scratch: f2W^T (after ctx dead)
  u16* PO  = Qb;
  u16* X1  = Kb;
  u16* Hq  = Vb;
  u16* Y   = Qb;

  dim3 blk(256);
  cvt_k<<<dim3(4096), blk, 0, stream>>>(x, xb, 4096 * 1024);
  // QKV projections
  transpose_cvt_k<<<dim3(16, 16), blk, 0, stream>>>(Wq, WT, 1024, 1024);
  gemm_bt<1><<<dim3(8, 32), blk, 0, stream>>>(xb, WT, Qb, bq, tw, 4096, 1024, 1024);
  transpose_cvt_k<<<dim3(16, 16), blk, 0, stream>>>(Wk, WT, 1024, 1024);
  gemm_bt<0><<<dim3(8, 32), blk, 0, stream>>>(xb, WT, Kb, bk, nullptr, 4096, 1024, 1024);
  transpose_cvt_k<<<dim3(16, 16), blk, 0, stream>>>(Wv, WT, 1024, 1024);
  gemm_bt<0><<<dim3(8, 32), blk, 0, stream>>>(xb, WT, Vb, bv, nullptr, 4096, 1024, 1024);
  // attention (ctx -> d_out scratch)
  attn_k<<<dim3(1024), blk, 0, stream>>>(Qb, Kb, Vb, CT, mask, gW, gb, temp);
  // output projection + LN/residual/LN
  transpose_cvt_k<<<dim3(16, 16), blk, 0, stream>>>(Wo, WT, 1024, 1024);
  gemm_bt<0><<<dim3(8, 32), blk, 0, stream>>>(CT, WT, PO, bo, nullptr, 4096, 1024, 1024);
  ln1_k<<<dim3(4096), blk, 0, stream>>>(PO, x, lag, lab, n1g, n1b, X1);
  // FFN in 4 row-quarters (Hq = 8 MiB, reused; V dead; f2W^T in d_out)
  transpose_cvt_k<<<dim3(64, 16), blk, 0, stream>>>(f1W, WT, 1024, 4096);
  transpose_cvt_k<<<dim3(16, 64), blk, 0, stream>>>(f2W, WT2, 4096, 1024);
  for (int qi = 0; qi < 4; qi++) {
    const u16* Aq = X1 + (size_t)qi * 1024 * 1024;
    u16* Yq = Y + (size_t)qi * 1024 * 1024;
    gemm_bt<2><<<dim3(32, 8), blk, 0, stream>>>(Aq, WT, Hq, f1b, nullptr, 1024, 4096, 1024);
    gemm_bt<0><<<dim3(8, 8), blk, 0, stream>>>(Hq, WT2, Yq, f2b, nullptr, 1024, 1024, 4096);
  }
  ln2_k<<<dim3(4096), blk, 0, stream>>>(Y, X1, n2g, n2b, out);
}

// Round 7
// 641.991 us; speedup vs baseline: 1.4662x; 1.4662x over previous
//
#include <hip/hip_runtime.h>
#include <stdint.h>
#include <math.h>

// ---------------------------------------------------------------------------
// EncoderLayer. I/O fp32 (mask int32). Internal bf16 MFMA, fp32 accum.
// R7: fix qkv_gemm weight addressing (separate WqT/WkT/WvT pointers; the
// z*1Mi stride assumption read poison for K/V in R5/R6). Keeps: mask bitpack,
// V pre-transpose, global_load_lds staging, fused QKV, FFN halves.
// ---------------------------------------------------------------------------

typedef uint16_t u16;
typedef unsigned long long u64;
typedef __attribute__((ext_vector_type(8))) short short8;   // 8 x bf16
typedef __attribute__((ext_vector_type(4))) float f32x4;

#define S_LEN 2048
#define DM 1024

#define GLOAD_LDS16(g, l)                                                      \
  __builtin_amdgcn_global_load_lds(                                            \
      (const __attribute__((address_space(1))) void*)(g),                      \
      (__attribute__((address_space(3))) void*)(l), 16, 0, 0)

__device__ __forceinline__ float bf2f(u16 h) {
  union { uint32_t u; float f; } x;
  x.u = ((uint32_t)h) << 16;
  return x.f;
}
__device__ __forceinline__ u16 f2bf(float f) {
  union { float f; uint32_t u; } x;
  x.f = f;
  uint32_t r = (x.u + 0x7fffu + ((x.u >> 16) & 1u)) >> 16;  // RNE
  return (u16)r;
}

union U8 { uint4 u; u16 s[8]; };
union U4 { uint2 u; u16 s[4]; };

// ---------------------------------------------------------------------------
// fp32 -> bf16 elementwise
// ---------------------------------------------------------------------------
__global__ __launch_bounds__(256) void cvt_k(const float* __restrict__ in,
                                             u16* __restrict__ out, int n) {
  int i = (blockIdx.x * 256 + threadIdx.x) * 4;
  if (i >= n) return;
  float4 v = *(const float4*)(in + i);
  U4 o;
  o.s[0] = f2bf(v.x); o.s[1] = f2bf(v.y); o.s[2] = f2bf(v.z); o.s[3] = f2bf(v.w);
  *(uint2*)(out + i) = o.u;
}

// ---------------------------------------------------------------------------
// mask int32 [2048,2048] -> bitpacked u16 [2048,128] (bit j = mask!=0)
// ---------------------------------------------------------------------------
__global__ __launch_bounds__(256) void mb_k(const int* __restrict__ mask,
                                            u16* __restrict__ mb) {
  int tid = blockIdx.x * 256 + threadIdx.x;      // 0..262143
  const int* src = mask + (size_t)tid * 16;
  uint32_t b = 0;
#pragma unroll
  for (int q = 0; q < 4; q++) {
    int4 m = *(const int4*)(src + q * 4);
    b |= (m.x != 0 ? 1u : 0u) << (q * 4 + 0);
    b |= (m.y != 0 ? 1u : 0u) << (q * 4 + 1);
    b |= (m.z != 0 ? 1u : 0u) << (q * 4 + 2);
    b |= (m.w != 0 ? 1u : 0u) << (q * 4 + 3);
  }
  mb[tid] = (u16)b;
}

// ---------------------------------------------------------------------------
// Weight convert+transpose: fp32 [R,C] -> bf16 [C,R]. grid(C/64,R/64)
// ---------------------------------------------------------------------------
__global__ __launch_bounds__(256) void transpose_cvt_k(const float* __restrict__ in,
                                                       u16* __restrict__ out,
                                                       int R, int C) {
  __shared__ u16 tile[64][72];
  int c0 = blockIdx.x * 64, r0 = blockIdx.y * 64;
  int t = threadIdx.x;
  int r = t & 63, seg = t >> 6;
  const float* src = in + (size_t)(r0 + r) * C + c0 + seg * 16;
#pragma unroll
  for (int q = 0; q < 4; q++) {
    float4 v = *(const float4*)(src + q * 4);
    tile[r][seg * 16 + q * 4 + 0] = f2bf(v.x);
    tile[r][seg * 16 + q * 4 + 1] = f2bf(v.y);
    tile[r][seg * 16 + q * 4 + 2] = f2bf(v.z);
    tile[r][seg * 16 + q * 4 + 3] = f2bf(v.w);
  }
  __syncthreads();
  U8 v0, v1;
#pragma unroll
  for (int i = 0; i < 8; i++) v0.s[i] = tile[seg * 16 + i][r];
#pragma unroll
  for (int i = 0; i < 8; i++) v1.s[i] = tile[seg * 16 + 8 + i][r];
  u16* dst = out + (size_t)(c0 + r) * R + r0 + seg * 16;
  *(uint4*)dst = v0.u;
  *(uint4*)(dst + 8) = v1.u;
}

// ---------------------------------------------------------------------------
// V [2*2048,1024] bf16 -> VT [(b*16+h)*64 + d][2048] bf16. grid(32 ktile, 32 bh)
// ---------------------------------------------------------------------------
__global__ __launch_bounds__(256) void vtrans_k(const u16* __restrict__ V,
                                                u16* __restrict__ VT) {
  __shared__ u16 tile[64][72];
  int bx = blockIdx.x, bh = blockIdx.y;
  int b = bh >> 4, h = bh & 15;
  int t = threadIdx.x, r = t & 63, seg = t >> 6;
  const u16* src = V + (size_t)(b * S_LEN + bx * 64 + r) * DM + h * 64 + seg * 16;
  *(uint4*)&tile[r][seg * 16] = *(const uint4*)src;
  *(uint4*)&tile[r][seg * 16 + 8] = *(const uint4*)(src + 8);
  __syncthreads();
  U8 v0, v1;
#pragma unroll
  for (int i = 0; i < 8; i++) v0.s[i] = tile[seg * 16 + i][r];
#pragma unroll
  for (int i = 0; i < 8; i++) v1.s[i] = tile[seg * 16 + 8 + i][r];
  u16* dst = VT + ((size_t)bh * 64 + r) * S_LEN + bx * 64 + seg * 16;
  *(uint4*)dst = v0.u;
  *(uint4*)(dst + 8) = v1.u;
}

// ---------------------------------------------------------------------------
// bf16 GEMM (m97 staging): C[M,N] = A[M,K] @ Bt[N,K]^T, 128x128, BK=32.
// EPI: 0=+bias ; 2=+bias then exact GELU
// ---------------------------------------------------------------------------
template <int EPI>
__global__ __launch_bounds__(256) void gemm_bt(const u16* __restrict__ A,
                                               const u16* __restrict__ Bt,
                                               u16* __restrict__ C,
                                               const float* __restrict__ bias,
                                               int M, int N, int K) {
  __shared__ u16 As[128 * 32];
  __shared__ u16 Bs[128 * 32];
  int t = threadIdx.x;
  int wid = t >> 6, lane = t & 63;
  int g = lane >> 4, li = lane & 15;
  int bx = blockIdx.x, by = blockIdx.y;
  int wr = (wid >> 1) * 64, wc = (wid & 1) * 64;

  const u16* a0 = A + (size_t)(by * 128 + wid * 32 + (lane >> 2)) * K + (lane & 3) * 8;
  const u16* b0 = Bt + (size_t)(bx * 128 + wid * 32 + (lane >> 2)) * K + (lane & 3) * 8;
  u16* lA0 = &As[wid * 1024];
  u16* lB0 = &Bs[wid * 1024];

  f32x4 acc[4][4];
#pragma unroll
  for (int i = 0; i < 4; i++)
#pragma unroll
    for (int j = 0; j < 4; j++) acc[i][j] = (f32x4){0.f, 0.f, 0.f, 0.f};

  for (int k0 = 0; k0 < K; k0 += 32) {
    GLOAD_LDS16(a0 + k0, lA0);
    GLOAD_LDS16(a0 + (size_t)16 * K + k0, lA0 + 512);
    GLOAD_LDS16(b0 + k0, lB0);
    GLOAD_LDS16(b0 + (size_t)16 * K + k0, lB0 + 512);
    __syncthreads();
    short8 af[4], bfv[4];
#pragma unroll
    for (int i = 0; i < 4; i++)
      af[i] = *(const short8*)&As[(wr + i * 16 + li) * 32 + g * 8];
#pragma unroll
    for (int i = 0; i < 4; i++)
      bfv[i] = *(const short8*)&Bs[(wc + i * 16 + li) * 32 + g * 8];
#pragma unroll
    for (int mi = 0; mi < 4; mi++)
#pragma unroll
      for (int ni = 0; ni < 4; ni++)
        acc[mi][ni] = __builtin_amdgcn_mfma_f32_16x16x32_bf16(
            af[mi], bfv[ni], acc[mi][ni], 0, 0, 0);
    __syncthreads();
  }

#pragma unroll
  for (int ni = 0; ni < 4; ni++) {
    int col = bx * 128 + wc + ni * 16 + li;
    float bv = bias[col];
#pragma unroll
    for (int mi = 0; mi < 4; mi++) {
#pragma unroll
      for (int r = 0; r < 4; r++) {
        int row = by * 128 + wr + mi * 16 + g * 4 + r;
        float v = acc[mi][ni][r] + bv;
        if (EPI == 2) v = 0.5f * v * (1.0f + erff(v * 0.70710678118654752f));
        C[(size_t)row * N + col] = f2bf(v);
      }
    }
  }
}

// ---------------------------------------------------------------------------
// Fused QKV projection: grid (8, 32, 3); z selects weight/bias/output.
// Weights passed as SEPARATE pointers (ws slots are 4Mi-elem apart; the old
// WTbase + z*1Mi addressing read poison for K/V -- R5/R6 bug).
// z==0 (Q) adds time_weights. M=4096, N=1024, K=1024.
// ---------------------------------------------------------------------------
__global__ __launch_bounds__(256) void qkv_gemm(const u16* __restrict__ A,
                                                const u16* __restrict__ WTq,
                                                const u16* __restrict__ WTk,
                                                const u16* __restrict__ WTv,
                                                u16* __restrict__ Cq,
                                                u16* __restrict__ Ck,
                                                u16* __restrict__ Cv,
                                                const float* __restrict__ bq,
                                                const float* __restrict__ bk,
                                                const float* __restrict__ bv,
                                                const float* __restrict__ tw) {
  const int K = 1024, N = 1024;
  __shared__ u16 As[128 * 32];
  __shared__ u16 Bs[128 * 32];
  int t = threadIdx.x;
  int wid = t >> 6, lane = t & 63;
  int g = lane >> 4, li = lane & 15;
  int bx = blockIdx.x, by = blockIdx.y, z = blockIdx.z;
  int wr = (wid >> 1) * 64, wc = (wid & 1) * 64;

  const u16* Bt = (z == 0) ? WTq : (z == 1) ? WTk : WTv;
  u16* C = (z == 0) ? Cq : (z == 1) ? Ck : Cv;
  const float* bias = (z == 0) ? bq : (z == 1) ? bk : bv;

  const u16* a0 = A + (size_t)(by * 128 + wid * 32 + (lane >> 2)) * K + (lane & 3) * 8;
  const u16* b0 = Bt + (size_t)(bx * 128 + wid * 32 + (lane >> 2)) * K + (lane & 3) * 8;
  u16* lA0 = &As[wid * 1024];
  u16* lB0 = &Bs[wid * 1024];

  f32x4 acc[4][4];
#pragma unroll
  for (int i = 0; i < 4; i++)
#pragma unroll
    for (int j = 0; j < 4; j++) acc[i][j] = (f32x4){0.f, 0.f, 0.f, 0.f};

  for (int k0 = 0; k0 < K; k0 += 32) {
    GLOAD_LDS16(a0 + k0, lA0);
    GLOAD_LDS16(a0 + (size_t)16 * K + k0, lA0 + 512);
    GLOAD_LDS16(b0 + k0, lB0);
    GLOAD_LDS16(b0 + (size_t)16 * K + k0, lB0 + 512);
    __syncthreads();
    short8 af[4], bfv[4];
#pragma unroll
    for (int i = 0; i < 4; i++)
      af[i] = *(const short8*)&As[(wr + i * 16 + li) * 32 + g * 8];
#pragma unroll
    for (int i = 0; i < 4; i++)
      bfv[i] = *(const short8*)&Bs[(wc + i * 16 + li) * 32 + g * 8];
#pragma unroll
    for (int mi = 0; mi < 4; mi++)
#pragma unroll
      for (int ni = 0; ni < 4; ni++)
        acc[mi][ni] = __builtin_amdgcn_mfma_f32_16x16x32_bf16(
            af[mi], bfv[ni], acc[mi][ni], 0, 0, 0);
    __syncthreads();
  }

#pragma unroll
  for (int ni = 0; ni < 4; ni++) {
    int col = bx * 128 + wc + ni * 16 + li;
    float bvv = bias[col];
    if (z == 0) bvv += tw[col];
#pragma unroll
    for (int mi = 0; mi < 4; mi++) {
#pragma unroll
      for (int r = 0; r < 4; r++) {
        int row = by * 128 + wr + mi * 16 + g * 4 + r;
        C[(size_t)row * N + col] = f2bf(acc[mi][ni][r] + bvv);
      }
    }
  }
}

// ---------------------------------------------------------------------------
// Flash attention. grid 1024 (b,h,qtile), 256 thr. V pre-transposed (VT),
// mask pre-bitpacked (mb: u16 [2048][128]).
// ---------------------------------------------------------------------------
__global__ __launch_bounds__(256) void attn_k(const u16* __restrict__ Q,
                                              const u16* __restrict__ Kp,
                                              const u16* __restrict__ VT,
                                              u16* __restrict__ CTX,
                                              const u16* __restrict__ mb,
                                              const float* __restrict__ gateW,
                                              const float* __restrict__ gateb,
                                              const float* __restrict__ temp) {
  __shared__ u16 Qs[64][72];
  __shared__ u16 Ks[64][72];      // K tile: [kpos][d]
  __shared__ u16 Vs[64][72];      // V^T tile: [d][kpos]
  __shared__ u16 Ps[4][16][72];   // per-wave P bounce
  __shared__ float gate_s[64];

  int blk = blockIdx.x;
  int qt = blk & 31, h = (blk >> 5) & 15, b = blk >> 9;
  int t = threadIdx.x, wid = t >> 6, lane = t & 63;
  int g = lane >> 4, li = lane & 15;
  int sq0 = qt * 64;

  const u16* Qb  = Q + ((size_t)b * S_LEN) * DM + h * 64;
  const u16* Kb  = Kp + ((size_t)b * S_LEN) * DM + h * 64;
  const u16* VTb = VT + ((size_t)(b * 16 + h) * 64) * S_LEN;

  {
    int r = t >> 2, cs = (t & 3) * 16;
    const u16* src = Qb + (size_t)(sq0 + r) * DM + cs;
    *(uint4*)&Qs[r][cs] = *(const uint4*)src;
    *(uint4*)&Qs[r][cs + 8] = *(const uint4*)(src + 8);
  }
  __syncthreads();
  if (t < 64) {
    float acc = gateb[0];
#pragma unroll
    for (int d = 0; d < 64; d++) acc += bf2f(Qs[t][d]) * gateW[d];
    gate_s[t] = 1.f / (1.f + __expf(-acc));
  }
  __syncthreads();

  float invt = 1.f / temp[0];
  short8 qf0 = *(const short8*)&Qs[wid * 16 + li][g * 8];
  short8 qf1 = *(const short8*)&Qs[wid * 16 + li][32 + g * 8];
  float gq[4];
  int sq[4];
#pragma unroll
  for (int r = 0; r < 4; r++) {
    gq[r] = gate_s[wid * 16 + g * 4 + r];
    sq[r] = sq0 + wid * 16 + g * 4 + r;
  }

  float m_i[4], l_i[4];
  f32x4 o[4];
#pragma unroll
  for (int r = 0; r < 4; r++) { m_i[r] = -1e30f; l_i[r] = 0.f; }
#pragma unroll
  for (int n = 0; n < 4; n++) o[n] = (f32x4){0.f, 0.f, 0.f, 0.f};

  for (int kt = 0; kt < 32; kt++) {
    __syncthreads();
    {
      int r = t >> 2, cs = (t & 3) * 16;
      const u16* srcK = Kb + (size_t)(kt * 64 + r) * DM + cs;
      *(uint4*)&Ks[r][cs] = *(const uint4*)srcK;
      *(uint4*)&Ks[r][cs + 8] = *(const uint4*)(srcK + 8);
      const u16* srcV = VTb + (size_t)r * S_LEN + kt * 64 + cs;
      *(uint4*)&Vs[r][cs] = *(const uint4*)srcV;
      *(uint4*)&Vs[r][cs + 8] = *(const uint4*)(srcV + 8);
    }
    __syncthreads();

    // S = Q K^T
    f32x4 sc[4];
#pragma unroll
    for (int ni = 0; ni < 4; ni++) {
      sc[ni] = (f32x4){0.f, 0.f, 0.f, 0.f};
      short8 kf0 = *(const short8*)&Ks[ni * 16 + li][g * 8];
      short8 kf1 = *(const short8*)&Ks[ni * 16 + li][32 + g * 8];
      sc[ni] = __builtin_amdgcn_mfma_f32_16x16x32_bf16(qf0, kf0, sc[ni], 0, 0, 0);
      sc[ni] = __builtin_amdgcn_mfma_f32_16x16x32_bf16(qf1, kf1, sc[ni], 0, 0, 0);
    }

    // 64 mask bits for kpos [kt*64, kt*64+64): u16 indices [kt*4, kt*4+4)
    u64 bits[4];
#pragma unroll
    for (int r = 0; r < 4; r++)
      bits[r] = *(const u64*)(mb + (size_t)sq[r] * 128 + kt * 4);

    float sval[4][4];
    float rmax[4] = {-1e30f, -1e30f, -1e30f, -1e30f};
#pragma unroll
    for (int ni = 0; ni < 4; ni++) {
#pragma unroll
      for (int r = 0; r < 4; r++) {
        float s = sc[ni][r];
        s = ((bits[r] >> (ni * 16 + li)) & 1ull) ? s * invt : -1e9f;
        s *= gq[r];
        sval[ni][r] = s;
        rmax[r] = fmaxf(rmax[r], s);
      }
    }
#pragma unroll
    for (int off = 1; off < 16; off <<= 1)
#pragma unroll
      for (int r = 0; r < 4; r++)
        rmax[r] = fmaxf(rmax[r], __shfl_xor(rmax[r], off, 64));

    float alpha[4], psum[4];
#pragma unroll
    for (int r = 0; r < 4; r++) {
      float mnew = fmaxf(m_i[r], rmax[r]);
      alpha[r] = __expf(m_i[r] - mnew);
      m_i[r] = mnew;
      psum[r] = 0.f;
    }
#pragma unroll
    for (int ni = 0; ni < 4; ni++)
#pragma unroll
      for (int r = 0; r < 4; r++) {
        float p = __expf(sval[ni][r] - m_i[r]);
        psum[r] += p;
        Ps[wid][g * 4 + r][ni * 16 + li] = f2bf(p);
      }
#pragma unroll
    for (int off = 1; off < 16; off <<= 1)
#pragma unroll
      for (int r = 0; r < 4; r++) psum[r] += __shfl_xor(psum[r], off, 64);
#pragma unroll
    for (int r = 0; r < 4; r++) l_i[r] = l_i[r] * alpha[r] + psum[r];
#pragma unroll
    for (int n = 0; n < 4; n++)
#pragma unroll
      for (int r = 0; r < 4; r++) o[n][r] *= alpha[r];

    __syncthreads();  // fence Ps stores before re-read

    short8 pf0 = *(const short8*)&Ps[wid][li][g * 8];
    short8 pf1 = *(const short8*)&Ps[wid][li][32 + g * 8];
#pragma unroll
    for (int ni = 0; ni < 4; ni++) {
      short8 vf0 = *(const short8*)&Vs[ni * 16 + li][g * 8];
      short8 vf1 = *(const short8*)&Vs[ni * 16 + li][32 + g * 8];
      o[ni] = __builtin_amdgcn_mfma_f32_16x16x32_bf16(pf0, vf0, o[ni], 0, 0, 0);
      o[ni] = __builtin_amdgcn_mfma_f32_16x16x32_bf16(pf1, vf1, o[ni], 0, 0, 0);
    }
  }

#pragma unroll
  for (int r = 0; r < 4; r++) l_i[r] = 1.f / l_i[r];
#pragma unroll
  for (int ni = 0; ni < 4; ni++) {
    int col = h * 64 + ni * 16 + li;
#pragma unroll
    for (int r = 0; r < 4; r++) {
      size_t row = (size_t)b * S_LEN + sq[r];
      CTX[row * DM + col] = f2bf(o[ni][r] * l_i[r]);
    }
  }
}

// ---------------------------------------------------------------------------
// LayerNorm kernels. One block per row.
// ---------------------------------------------------------------------------
__device__ __forceinline__ void block_sum2(float& a, float& b, float* red, int t) {
#pragma unroll
  for (int off = 32; off > 0; off >>= 1) {
    a += __shfl_xor(a, off, 64);
    b += __shfl_xor(b, off, 64);
  }
  __syncthreads();
  if ((t & 63) == 0) {
    red[(t >> 6) * 2] = a;
    red[(t >> 6) * 2 + 1] = b;
  }
  __syncthreads();
  a = red[0] + red[2] + red[4] + red[6];
  b = red[1] + red[3] + red[5] + red[7];
}

__global__ __launch_bounds__(256) void ln1_k(const u16* __restrict__ po,
                                             const float* __restrict__ x,
                                             const float* __restrict__ g1,
                                             const float* __restrict__ b1,
                                             const float* __restrict__ g2,
                                             const float* __restrict__ b2,
                                             u16* __restrict__ x1) {
  __shared__ float red[8];
  int row = blockIdx.x, t = threadIdx.x;
  size_t base = (size_t)row * 1024 + t * 4;
  U4 pv; pv.u = *(const uint2*)(po + base);
  float v[4];
#pragma unroll
  for (int i = 0; i < 4; i++) v[i] = bf2f(pv.s[i]);
  float s1 = v[0] + v[1] + v[2] + v[3];
  float s2 = v[0]*v[0] + v[1]*v[1] + v[2]*v[2] + v[3]*v[3];
  block_sum2(s1, s2, red, t);
  float mu = s1 * (1.f / 1024.f);
  float rs = rsqrtf(s2 * (1.f / 1024.f) - mu * mu + 1e-5f);
  float4 xv = *(const float4*)(x + base);
  float4 g1v = *(const float4*)(g1 + t * 4);
  float4 b1v = *(const float4*)(b1 + t * 4);
  float w[4];
  w[0] = xv.x + ((v[0] - mu) * rs * g1v.x + b1v.x);
  w[1] = xv.y + ((v[1] - mu) * rs * g1v.y + b1v.y);
  w[2] = xv.z + ((v[2] - mu) * rs * g1v.z + b1v.z);
  w[3] = xv.w + ((v[3] - mu) * rs * g1v.w + b1v.w);
  s1 = w[0] + w[1] + w[2] + w[3];
  s2 = w[0]*w[0] + w[1]*w[1] + w[2]*w[2] + w[3]*w[3];
  block_sum2(s1, s2, red, t);
  mu = s1 * (1.f / 1024.f);
  rs = rsqrtf(s2 * (1.f / 1024.f) - mu * mu + 1e-5f);
  float4 g2v = *(const float4*)(g2 + t * 4);
  float4 b2v = *(const float4*)(b2 + t * 4);
  U4 ov;
  ov.s[0] = f2bf((w[0] - mu) * rs * g2v.x + b2v.x);
  ov.s[1] = f2bf((w[1] - mu) * rs * g2v.y + b2v.y);
  ov.s[2] = f2bf((w[2] - mu) * rs * g2v.z + b2v.z);
  ov.s[3] = f2bf((w[3] - mu) * rs * g2v.w + b2v.w);
  *(uint2*)(x1 + base) = ov.u;
}

__global__ __launch_bounds__(256) void ln2_k(const u16* __restrict__ y,
                                             const u16* __restrict__ x1,
                                             const float* __restrict__ g,
                                             const float* __restrict__ b,
                                             float* __restrict__ out) {
  __shared__ float red[8];
  int row = blockIdx.x, t = threadIdx.x;
  size_t base = (size_t)row * 1024 + t * 4;
  U4 yv; yv.u = *(const uint2*)(y + base);
  U4 xv; xv.u = *(const uint2*)(x1 + base);
  float w[4];
#pragma unroll
  for (int i = 0; i < 4; i++) w[i] = bf2f(yv.s[i]) + bf2f(xv.s[i]);
  float s1 = w[0] + w[1] + w[2] + w[3];
  float s2 = w[0]*w[0] + w[1]*w[1] + w[2]*w[2] + w[3]*w[3];
  block_sum2(s1, s2, red, t);
  float mu = s1 * (1.f / 1024.f);
  float rs = rsqrtf(s2 * (1.f / 1024.f) - mu * mu + 1e-5f);
  float4 gv = *(const float4*)(g + t * 4);
  float4 bv = *(const float4*)(b + t * 4);
  float4 ov;
  ov.x = (w[0] - mu) * rs * gv.x + bv.x;
  ov.y = (w[1] - mu) * rs * gv.y + bv.y;
  ov.z = (w[2] - mu) * rs * gv.z + bv.z;
  ov.w = (w[3] - mu) * rs * gv.w + bv.w;
  *(float4*)(out + base) = ov;
}

// ---------------------------------------------------------------------------
extern "C" void kernel_launch(void* const* d_in, const int* in_sizes, int n_in,
                              void* d_out, int out_size, void* d_ws, size_t ws_size,
                              hipStream_t stream) {
  (void)in_sizes; (void)n_in; (void)out_size; (void)ws_size;
  const float* x    = (const float*)d_in[0];
  const int*   mask = (const int*)d_in[1];
  const float* Wq = (const float*)d_in[2];  const float* bq = (const float*)d_in[3];
  const float* Wk = (const float*)d_in[4];  const float* bk = (const float*)d_in[5];
  const float* Wv = (const float*)d_in[6];  const float* bv = (const float*)d_in[7];
  const float* Wo = (const float*)d_in[8];  const float* bo = (const float*)d_in[9];
  const float* temp = (const float*)d_in[10];
  const float* tw   = (const float*)d_in[11];
  const float* gW   = (const float*)d_in[12]; const float* gb  = (const float*)d_in[13];
  const float* lag  = (const float*)d_in[14]; const float* lab = (const float*)d_in[15];
  const float* f1W  = (const float*)d_in[16]; const float* f1b = (const float*)d_in[17];
  const float* f2W  = (const float*)d_in[18]; const float* f2b = (const float*)d_in[19];
  const float* n1g  = (const float*)d_in[20]; const float* n1b = (const float*)d_in[21];
  const float* n2g  = (const float*)d_in[22]; const float* n2b = (const float*)d_in[23];
  float* out = (float*)d_out;

  // ws: 5 bf16 slots (40 MiB) + d_out as 2 bf16 slots (16 MiB).
  //  s0: WqT  -> VT      -> f1WT
  //  s1: WkT  -> maskbits-> f2WT
  //  s2: WvT  -> CT      -> Y
  //  s3: Q    -> X1
  //  s4: xb
  //  d0: K    -> PO      -> H(lower)
  //  d1: V    -> WoT     -> H(upper)   ... ln2 finally writes fp32 out over d0-d1
  u16* ws = (u16*)d_ws;
  const size_t MB4 = (size_t)4096 * 1024;
  u16* s0 = ws;
  u16* s1 = ws + 1 * MB4;
  u16* s2 = ws + 2 * MB4;
  u16* s3 = ws + 3 * MB4;
  u16* s4 = ws + 4 * MB4;
  u16* d0 = (u16*)d_out;
  u16* d1 = d0 + MB4;

  dim3 blk(256);
  cvt_k<<<dim3(4096), blk, 0, stream>>>(x, s4, 4096 * 1024);
  transpose_cvt_k<<<dim3(16, 16), blk, 0, stream>>>(Wq, s0, 1024, 1024);
  transpose_cvt_k<<<dim3(16, 16), blk, 0, stream>>>(Wk, s1, 1024, 1024);
  transpose_cvt_k<<<dim3(16, 16), blk, 0, stream>>>(Wv, s2, 1024, 1024);
  // fused QKV: Q->s3, K->d0, V->d1
  qkv_gemm<<<dim3(8, 32, 3), blk, 0, stream>>>(s4, s0, s1, s2, s3, d0, d1,
                                               bq, bk, bv, tw);
  // V -> VT (s0, WqT dead); mask -> bits (s1, WkT dead)
  vtrans_k<<<dim3(32, 32), blk, 0, stream>>>(d1, s0);
  mb_k<<<dim3(1024), blk, 0, stream>>>(mask, s1);
  // attention: ctx -> s2 (WvT dead)
  attn_k<<<dim3(1024), blk, 0, stream>>>(s3, d0, s0, s2, s1, gW, gb, temp);
  // Wo projection: WoT -> d1 (V dead); PO -> d0 (K dead)
  transpose_cvt_k<<<dim3(16, 16), blk, 0, stream>>>(Wo, d1, 1024, 1024);
  gemm_bt<0><<<dim3(8, 32), blk, 0, stream>>>(s2, d1, d0, bo, 4096, 1024, 1024);
  // LN(attn)+residual+LN: X1 -> s3 (Q dead)
  ln1_k<<<dim3(4096), blk, 0, stream>>>(d0, x, lag, lab, n1g, n1b, s3);
  // FFN: f1WT -> s0 (VT dead), f2WT -> s1 (bits dead), H -> d0-d1 (16 MiB)
  transpose_cvt_k<<<dim3(64, 16), blk, 0, stream>>>(f1W, s0, 1024, 4096);
  transpose_cvt_k<<<dim3(16, 64), blk, 0, stream>>>(f2W, s1, 4096, 1024);
  for (int i = 0; i < 2; i++) {
    const u16* Ai = s3 + (size_t)i * 2048 * 1024;
    u16* Yi = s2 + (size_t)i * 2048 * 1024;   // Y -> s2 (CT dead)
    gemm_bt<2><<<dim3(32, 16), blk, 0, stream>>>(Ai, s0, d0, f1b, 2048, 4096, 1024);
    gemm_bt<0><<<dim3(8, 16), blk, 0, stream>>>(d0, s1, Yi, f2b, 2048, 1024, 4096);
  }
  // final LN -> fp32 out (H dead)
  ln2_k<<<dim3(4096), blk, 0, stream>>>(s2, s3, n2g, n2b, out);
}

// Round 8
// 579.884 us; speedup vs baseline: 1.6233x; 1.1071x over previous
//
#include <hip/hip_runtime.h>
#include <stdint.h>
#include <math.h>

// ---------------------------------------------------------------------------
// EncoderLayer. I/O fp32 (mask int32). Internal bf16 MFMA, fp32 accum.
// R8: attn XCD swizzle (bh in low bits -> K/V L2 locality), exp2-domain
// softmax, GEMM M-stripe XCD mapping + BM=64 tiles for Wo/fc2, merged
// QKV weight transposes. Layout/aliasing identical to R7 (passed).
// ---------------------------------------------------------------------------

typedef uint16_t u16;
typedef unsigned long long u64;
typedef __attribute__((ext_vector_type(8))) short short8;   // 8 x bf16
typedef __attribute__((ext_vector_type(4))) float f32x4;

#define S_LEN 2048
#define DM 1024

#define GLOAD_LDS16(g, l)                                                      \
  __builtin_amdgcn_global_load_lds(                                            \
      (const __attribute__((address_space(1))) void*)(g),                      \
      (__attribute__((address_space(3))) void*)(l), 16, 0, 0)

__device__ __forceinline__ float bf2f(u16 h) {
  union { uint32_t u; float f; } x;
  x.u = ((uint32_t)h) << 16;
  return x.f;
}
__device__ __forceinline__ u16 f2bf(float f) {
  union { float f; uint32_t u; } x;
  x.f = f;
  uint32_t r = (x.u + 0x7fffu + ((x.u >> 16) & 1u)) >> 16;  // RNE
  return (u16)r;
}

union U8 { uint4 u; u16 s[8]; };
union U4 { uint2 u; u16 s[4]; };

// ---------------------------------------------------------------------------
// fp32 -> bf16 elementwise
// ---------------------------------------------------------------------------
__global__ __launch_bounds__(256) void cvt_k(const float* __restrict__ in,
                                             u16* __restrict__ out, int n) {
  int i = (blockIdx.x * 256 + threadIdx.x) * 4;
  if (i >= n) return;
  float4 v = *(const float4*)(in + i);
  U4 o;
  o.s[0] = f2bf(v.x); o.s[1] = f2bf(v.y); o.s[2] = f2bf(v.z); o.s[3] = f2bf(v.w);
  *(uint2*)(out + i) = o.u;
}

// ---------------------------------------------------------------------------
// mask int32 [2048,2048] -> bitpacked u16 [2048,128] (bit j = mask!=0)
// ---------------------------------------------------------------------------
__global__ __launch_bounds__(256) void mb_k(const int* __restrict__ mask,
                                            u16* __restrict__ mb) {
  int tid = blockIdx.x * 256 + threadIdx.x;
  const int* src = mask + (size_t)tid * 16;
  uint32_t b = 0;
#pragma unroll
  for (int q = 0; q < 4; q++) {
    int4 m = *(const int4*)(src + q * 4);
    b |= (m.x != 0 ? 1u : 0u) << (q * 4 + 0);
    b |= (m.y != 0 ? 1u : 0u) << (q * 4 + 1);
    b |= (m.z != 0 ? 1u : 0u) << (q * 4 + 2);
    b |= (m.w != 0 ? 1u : 0u) << (q * 4 + 3);
  }
  mb[tid] = (u16)b;
}

// ---------------------------------------------------------------------------
// Weight convert+transpose: fp32 [R,C] -> bf16 [C,R]. grid(C/64,R/64)
// ---------------------------------------------------------------------------
__device__ __forceinline__ void tcvt_body(const float* __restrict__ in,
                                          u16* __restrict__ out, int R, int C) {
  __shared__ u16 tile[64][72];
  int c0 = blockIdx.x * 64, r0 = blockIdx.y * 64;
  int t = threadIdx.x;
  int r = t & 63, seg = t >> 6;
  const float* src = in + (size_t)(r0 + r) * C + c0 + seg * 16;
#pragma unroll
  for (int q = 0; q < 4; q++) {
    float4 v = *(const float4*)(src + q * 4);
    tile[r][seg * 16 + q * 4 + 0] = f2bf(v.x);
    tile[r][seg * 16 + q * 4 + 1] = f2bf(v.y);
    tile[r][seg * 16 + q * 4 + 2] = f2bf(v.z);
    tile[r][seg * 16 + q * 4 + 3] = f2bf(v.w);
  }
  __syncthreads();
  U8 v0, v1;
#pragma unroll
  for (int i = 0; i < 8; i++) v0.s[i] = tile[seg * 16 + i][r];
#pragma unroll
  for (int i = 0; i < 8; i++) v1.s[i] = tile[seg * 16 + 8 + i][r];
  u16* dst = out + (size_t)(c0 + r) * R + r0 + seg * 16;
  *(uint4*)dst = v0.u;
  *(uint4*)(dst + 8) = v1.u;
}

__global__ __launch_bounds__(256) void transpose_cvt_k(const float* __restrict__ in,
                                                       u16* __restrict__ out,
                                                       int R, int C) {
  tcvt_body(in, out, R, C);
}

// 3 square 1024x1024 transposes in one dispatch (z selects)
__global__ __launch_bounds__(256) void transpose_cvt3_k(const float* __restrict__ i0,
                                                        const float* __restrict__ i1,
                                                        const float* __restrict__ i2,
                                                        u16* __restrict__ o0,
                                                        u16* __restrict__ o1,
                                                        u16* __restrict__ o2) {
  int z = blockIdx.z;
  const float* in = (z == 0) ? i0 : (z == 1) ? i1 : i2;
  u16* out = (z == 0) ? o0 : (z == 1) ? o1 : o2;
  tcvt_body(in, out, 1024, 1024);
}

// ---------------------------------------------------------------------------
// V [2*2048,1024] bf16 -> VT [(b*16+h)*64 + d][2048] bf16. grid(32 ktile, 32 bh)
// ---------------------------------------------------------------------------
__global__ __launch_bounds__(256) void vtrans_k(const u16* __restrict__ V,
                                                u16* __restrict__ VT) {
  __shared__ u16 tile[64][72];
  int bx = blockIdx.x, bh = blockIdx.y;
  int b = bh >> 4, h = bh & 15;
  int t = threadIdx.x, r = t & 63, seg = t >> 6;
  const u16* src = V + (size_t)(b * S_LEN + bx * 64 + r) * DM + h * 64 + seg * 16;
  *(uint4*)&tile[r][seg * 16] = *(const uint4*)src;
  *(uint4*)&tile[r][seg * 16 + 8] = *(const uint4*)(src + 8);
  __syncthreads();
  U8 v0, v1;
#pragma unroll
  for (int i = 0; i < 8; i++) v0.s[i] = tile[seg * 16 + i][r];
#pragma unroll
  for (int i = 0; i < 8; i++) v1.s[i] = tile[seg * 16 + 8 + i][r];
  u16* dst = VT + ((size_t)bh * 64 + r) * S_LEN + bx * 64 + seg * 16;
  *(uint4*)dst = v0.u;
  *(uint4*)(dst + 8) = v1.u;
}

// ---------------------------------------------------------------------------
// bf16 GEMM: C[M,N] = A[M,K] @ Bt[N,K]^T. Tile BM x 128, BK=32, 4 waves.
// BM in {128, 64}. EPI: 0=+bias ; 2=+bias then exact GELU.
// MXS=1: M-tile is blockIdx.x (XCD gets an M-stripe; good when B fits L2).
// ---------------------------------------------------------------------------
template <int BM, int EPI, int MXS>
__global__ __launch_bounds__(256) void gemm_bt(const u16* __restrict__ A,
                                               const u16* __restrict__ Bt,
                                               u16* __restrict__ C,
                                               const float* __restrict__ bias,
                                               int M, int N, int K) {
  constexpr int MI = BM / 32;          // m-tiles per wave
  constexpr int RPW = BM / 4;          // A rows staged per wave
  __shared__ u16 As[BM * 32];
  __shared__ u16 Bs[128 * 32];
  int t = threadIdx.x;
  int wid = t >> 6, lane = t & 63;
  int g = lane >> 4, li = lane & 15;
  int bx = MXS ? blockIdx.y : blockIdx.x;   // N-tile
  int by = MXS ? blockIdx.x : blockIdx.y;   // M-tile
  int wr = (wid >> 1) * (BM / 2), wc = (wid & 1) * 64;

  const u16* a0 = A + (size_t)(by * BM + wid * RPW + (lane >> 2)) * K + (lane & 3) * 8;
  const u16* b0 = Bt + (size_t)(bx * 128 + wid * 32 + (lane >> 2)) * K + (lane & 3) * 8;
  u16* lA0 = &As[wid * RPW * 32];
  u16* lB0 = &Bs[wid * 1024];

  f32x4 acc[MI][4];
#pragma unroll
  for (int i = 0; i < MI; i++)
#pragma unroll
    for (int j = 0; j < 4; j++) acc[i][j] = (f32x4){0.f, 0.f, 0.f, 0.f};

  for (int k0 = 0; k0 < K; k0 += 32) {
    GLOAD_LDS16(a0 + k0, lA0);
    if (BM == 128) GLOAD_LDS16(a0 + (size_t)16 * K + k0, lA0 + 512);
    GLOAD_LDS16(b0 + k0, lB0);
    GLOAD_LDS16(b0 + (size_t)16 * K + k0, lB0 + 512);
    __syncthreads();
    short8 af[MI], bfv[4];
#pragma unroll
    for (int i = 0; i < MI; i++)
      af[i] = *(const short8*)&As[(wr + i * 16 + li) * 32 + g * 8];
#pragma unroll
    for (int i = 0; i < 4; i++)
      bfv[i] = *(const short8*)&Bs[(wc + i * 16 + li) * 32 + g * 8];
#pragma unroll
    for (int mi = 0; mi < MI; mi++)
#pragma unroll
      for (int ni = 0; ni < 4; ni++)
        acc[mi][ni] = __builtin_amdgcn_mfma_f32_16x16x32_bf16(
            af[mi], bfv[ni], acc[mi][ni], 0, 0, 0);
    __syncthreads();
  }

#pragma unroll
  for (int ni = 0; ni < 4; ni++) {
    int col = bx * 128 + wc + ni * 16 + li;
    float bv = bias[col];
#pragma unroll
    for (int mi = 0; mi < MI; mi++) {
#pragma unroll
      for (int r = 0; r < 4; r++) {
        int row = by * BM + wr + mi * 16 + g * 4 + r;
        float v = acc[mi][ni][r] + bv;
        if (EPI == 2) v = 0.5f * v * (1.0f + erff(v * 0.70710678118654752f));
        C[(size_t)row * N + col] = f2bf(v);
      }
    }
  }
}

// ---------------------------------------------------------------------------
// Fused QKV projection: grid (32, 8, 3); x=M-tile, y=N-tile, z=weight.
// z==0 (Q) adds time_weights. M=4096, N=1024, K=1024.
// ---------------------------------------------------------------------------
__global__ __launch_bounds__(256) void qkv_gemm(const u16* __restrict__ A,
                                                const u16* __restrict__ WTq,
                                                const u16* __restrict__ WTk,
                                                const u16* __restrict__ WTv,
                                                u16* __restrict__ Cq,
                                                u16* __restrict__ Ck,
                                                u16* __restrict__ Cv,
                                                const float* __restrict__ bq,
                                                const float* __restrict__ bk,
                                                const float* __restrict__ bv,
                                                const float* __restrict__ tw) {
  const int K = 1024, N = 1024;
  __shared__ u16 As[128 * 32];
  __shared__ u16 Bs[128 * 32];
  int t = threadIdx.x;
  int wid = t >> 6, lane = t & 63;
  int g = lane >> 4, li = lane & 15;
  int by = blockIdx.x, bx = blockIdx.y, z = blockIdx.z;   // M in x
  int wr = (wid >> 1) * 64, wc = (wid & 1) * 64;

  const u16* Bt = (z == 0) ? WTq : (z == 1) ? WTk : WTv;
  u16* C = (z == 0) ? Cq : (z == 1) ? Ck : Cv;
  const float* bias = (z == 0) ? bq : (z == 1) ? bk : bv;

  const u16* a0 = A + (size_t)(by * 128 + wid * 32 + (lane >> 2)) * K + (lane & 3) * 8;
  const u16* b0 = Bt + (size_t)(bx * 128 + wid * 32 + (lane >> 2)) * K + (lane & 3) * 8;
  u16* lA0 = &As[wid * 1024];
  u16* lB0 = &Bs[wid * 1024];

  f32x4 acc[4][4];
#pragma unroll
  for (int i = 0; i < 4; i++)
#pragma unroll
    for (int j = 0; j < 4; j++) acc[i][j] = (f32x4){0.f, 0.f, 0.f, 0.f};

  for (int k0 = 0; k0 < K; k0 += 32) {
    GLOAD_LDS16(a0 + k0, lA0);
    GLOAD_LDS16(a0 + (size_t)16 * K + k0, lA0 + 512);
    GLOAD_LDS16(b0 + k0, lB0);
    GLOAD_LDS16(b0 + (size_t)16 * K + k0, lB0 + 512);
    __syncthreads();
    short8 af[4], bfv[4];
#pragma unroll
    for (int i = 0; i < 4; i++)
      af[i] = *(const short8*)&As[(wr + i * 16 + li) * 32 + g * 8];
#pragma unroll
    for (int i = 0; i < 4; i++)
      bfv[i] = *(const short8*)&Bs[(wc + i * 16 + li) * 32 + g * 8];
#pragma unroll
    for (int mi = 0; mi < 4; mi++)
#pragma unroll
      for (int ni = 0; ni < 4; ni++)
        acc[mi][ni] = __builtin_amdgcn_mfma_f32_16x16x32_bf16(
            af[mi], bfv[ni], acc[mi][ni], 0, 0, 0);
    __syncthreads();
  }

#pragma unroll
  for (int ni = 0; ni < 4; ni++) {
    int col = bx * 128 + wc + ni * 16 + li;
    float bvv = bias[col];
    if (z == 0) bvv += tw[col];
#pragma unroll
    for (int mi = 0; mi < 4; mi++) {
#pragma unroll
      for (int r = 0; r < 4; r++) {
        int row = by * 128 + wr + mi * 16 + g * 4 + r;
        C[(size_t)row * N + col] = f2bf(acc[mi][ni][r] + bvv);
      }
    }
  }
}

// ---------------------------------------------------------------------------
// Flash attention. grid 1024, 256 thr. Block swizzle: bh in LOW 5 bits so all
// 32 q-tiles of one (b,h) share an XCD (32 = 0 mod 8) -> K/V L2 locality.
// Softmax in exp2 domain (log2e folded into scale).
// ---------------------------------------------------------------------------
__global__ __launch_bounds__(256) void attn_k(const u16* __restrict__ Q,
                                              const u16* __restrict__ Kp,
                                              const u16* __restrict__ VT,
                                              u16* __restrict__ CTX,
                                              const u16* __restrict__ mb,
                                              const float* __restrict__ gateW,
                                              const float* __restrict__ gateb,
                                              const float* __restrict__ temp) {
  __shared__ u16 Qs[64][72];
  __shared__ u16 Ks[64][72];      // K tile: [kpos][d]
  __shared__ u16 Vs[64][72];      // V^T tile: [d][kpos]
  __shared__ u16 Ps[4][16][72];   // per-wave P bounce
  __shared__ float gate_s[64];

  int blk = blockIdx.x;
  int bh = blk & 31, qt = blk >> 5;          // XCD swizzle
  int b = bh >> 4, h = bh & 15;
  int t = threadIdx.x, wid = t >> 6, lane = t & 63;
  int g = lane >> 4, li = lane & 15;
  int sq0 = qt * 64;

  const u16* Qb  = Q + ((size_t)b * S_LEN) * DM + h * 64;
  const u16* Kb  = Kp + ((size_t)b * S_LEN) * DM + h * 64;
  const u16* VTb = VT + ((size_t)(b * 16 + h) * 64) * S_LEN;

  {
    int r = t >> 2, cs = (t & 3) * 16;
    const u16* src = Qb + (size_t)(sq0 + r) * DM + cs;
    *(uint4*)&Qs[r][cs] = *(const uint4*)src;
    *(uint4*)&Qs[r][cs + 8] = *(const uint4*)(src + 8);
  }
  __syncthreads();
  if (t < 64) {
    float acc = gateb[0];
#pragma unroll
    for (int d = 0; d < 64; d++) acc += bf2f(Qs[t][d]) * gateW[d];
    gate_s[t] = 1.f / (1.f + __expf(-acc));
  }
  __syncthreads();

  const float LOG2E = 1.4426950408889634f;
  float invt2 = LOG2E / temp[0];              // score scale in exp2 domain
  const float NEG2 = -1.442695e9f;            // -1e9 * log2e
  short8 qf0 = *(const short8*)&Qs[wid * 16 + li][g * 8];
  short8 qf1 = *(const short8*)&Qs[wid * 16 + li][32 + g * 8];
  float gq[4];
  int sq[4];
#pragma unroll
  for (int r = 0; r < 4; r++) {
    gq[r] = gate_s[wid * 16 + g * 4 + r];
    sq[r] = sq0 + wid * 16 + g * 4 + r;
  }

  float m_i[4], l_i[4];
  f32x4 o[4];
#pragma unroll
  for (int r = 0; r < 4; r++) { m_i[r] = -1e30f; l_i[r] = 0.f; }
#pragma unroll
  for (int n = 0; n < 4; n++) o[n] = (f32x4){0.f, 0.f, 0.f, 0.f};

  for (int kt = 0; kt < 32; kt++) {
    __syncthreads();
    {
      int r = t >> 2, cs = (t & 3) * 16;
      const u16* srcK = Kb + (size_t)(kt * 64 + r) * DM + cs;
      *(uint4*)&Ks[r][cs] = *(const uint4*)srcK;
      *(uint4*)&Ks[r][cs + 8] = *(const uint4*)(srcK + 8);
      const u16* srcV = VTb + (size_t)r * S_LEN + kt * 64 + cs;
      *(uint4*)&Vs[r][cs] = *(const uint4*)srcV;
      *(uint4*)&Vs[r][cs + 8] = *(const uint4*)(srcV + 8);
    }
    __syncthreads();

    // S = Q K^T
    f32x4 sc[4];
#pragma unroll
    for (int ni = 0; ni < 4; ni++) {
      sc[ni] = (f32x4){0.f, 0.f, 0.f, 0.f};
      short8 kf0 = *(const short8*)&Ks[ni * 16 + li][g * 8];
      short8 kf1 = *(const short8*)&Ks[ni * 16 + li][32 + g * 8];
      sc[ni] = __builtin_amdgcn_mfma_f32_16x16x32_bf16(qf0, kf0, sc[ni], 0, 0, 0);
      sc[ni] = __builtin_amdgcn_mfma_f32_16x16x32_bf16(qf1, kf1, sc[ni], 0, 0, 0);
    }

    u64 bits[4];
#pragma unroll
    for (int r = 0; r < 4; r++)
      bits[r] = *(const u64*)(mb + (size_t)sq[r] * 128 + kt * 4);

    float sval[4][4];
    float rmax[4] = {-1e30f, -1e30f, -1e30f, -1e30f};
#pragma unroll
    for (int ni = 0; ni < 4; ni++) {
#pragma unroll
      for (int r = 0; r < 4; r++) {
        float s = sc[ni][r];
        s = ((bits[r] >> (ni * 16 + li)) & 1ull) ? s * invt2 : NEG2;
        s *= gq[r];
        sval[ni][r] = s;
        rmax[r] = fmaxf(rmax[r], s);
      }
    }
#pragma unroll
    for (int off = 1; off < 16; off <<= 1)
#pragma unroll
      for (int r = 0; r < 4; r++)
        rmax[r] = fmaxf(rmax[r], __shfl_xor(rmax[r], off, 64));

    float alpha[4], psum[4];
#pragma unroll
    for (int r = 0; r < 4; r++) {
      float mnew = fmaxf(m_i[r], rmax[r]);
      alpha[r] = exp2f(m_i[r] - mnew);
      m_i[r] = mnew;
      psum[r] = 0.f;
    }
#pragma unroll
    for (int ni = 0; ni < 4; ni++)
#pragma unroll
      for (int r = 0; r < 4; r++) {
        float p = exp2f(sval[ni][r] - m_i[r]);
        psum[r] += p;
        Ps[wid][g * 4 + r][ni * 16 + li] = f2bf(p);
      }
#pragma unroll
    for (int off = 1; off < 16; off <<= 1)
#pragma unroll
      for (int r = 0; r < 4; r++) psum[r] += __shfl_xor(psum[r], off, 64);
#pragma unroll
    for (int r = 0; r < 4; r++) l_i[r] = l_i[r] * alpha[r] + psum[r];
#pragma unroll
    for (int n = 0; n < 4; n++)
#pragma unroll
      for (int r = 0; r < 4; r++) o[n][r] *= alpha[r];

    __syncthreads();  // fence Ps stores before re-read

    short8 pf0 = *(const short8*)&Ps[wid][li][g * 8];
    short8 pf1 = *(const short8*)&Ps[wid][li][32 + g * 8];
#pragma unroll
    for (int ni = 0; ni < 4; ni++) {
      short8 vf0 = *(const short8*)&Vs[ni * 16 + li][g * 8];
      short8 vf1 = *(const short8*)&Vs[ni * 16 + li][32 + g * 8];
      o[ni] = __builtin_amdgcn_mfma_f32_16x16x32_bf16(pf0, vf0, o[ni], 0, 0, 0);
      o[ni] = __builtin_amdgcn_mfma_f32_16x16x32_bf16(pf1, vf1, o[ni], 0, 0, 0);
    }
  }

#pragma unroll
  for (int r = 0; r < 4; r++) l_i[r] = 1.f / l_i[r];
#pragma unroll
  for (int ni = 0; ni < 4; ni++) {
    int col = h * 64 + ni * 16 + li;
#pragma unroll
    for (int r = 0; r < 4; r++) {
      size_t row = (size_t)b * S_LEN + sq[r];
      CTX[row * DM + col] = f2bf(o[ni][r] * l_i[r]);
    }
  }
}

// ---------------------------------------------------------------------------
// LayerNorm kernels. One block per row.
// ---------------------------------------------------------------------------
__device__ __forceinline__ void block_sum2(float& a, float& b, float* red, int t) {
#pragma unroll
  for (int off = 32; off > 0; off >>= 1) {
    a += __shfl_xor(a, off, 64);
    b += __shfl_xor(b, off, 64);
  }
  __syncthreads();
  if ((t & 63) == 0) {
    red[(t >> 6) * 2] = a;
    red[(t >> 6) * 2 + 1] = b;
  }
  __syncthreads();
  a = red[0] + red[2] + red[4] + red[6];
  b = red[1] + red[3] + red[5] + red[7];
}

__global__ __launch_bounds__(256) void ln1_k(const u16* __restrict__ po,
                                             const float* __restrict__ x,
                                             const float* __restrict__ g1,
                                             const float* __restrict__ b1,
                                             const float* __restrict__ g2,
                                             const float* __restrict__ b2,
                                             u16* __restrict__ x1) {
  __shared__ float red[8];
  int row = blockIdx.x, t = threadIdx.x;
  size_t base = (size_t)row * 1024 + t * 4;
  U4 pv; pv.u = *(const uint2*)(po + base);
  float v[4];
#pragma unroll
  for (int i = 0; i < 4; i++) v[i] = bf2f(pv.s[i]);
  float s1 = v[0] + v[1] + v[2] + v[3];
  float s2 = v[0]*v[0] + v[1]*v[1] + v[2]*v[2] + v[3]*v[3];
  block_sum2(s1, s2, red, t);
  float mu = s1 * (1.f / 1024.f);
  float rs = rsqrtf(s2 * (1.f / 1024.f) - mu * mu + 1e-5f);
  float4 xv = *(const float4*)(x + base);
  float4 g1v = *(const float4*)(g1 + t * 4);
  float4 b1v = *(const float4*)(b1 + t * 4);
  float w[4];
  w[0] = xv.x + ((v[0] - mu) * rs * g1v.x + b1v.x);
  w[1] = xv.y + ((v[1] - mu) * rs * g1v.y + b1v.y);
  w[2] = xv.z + ((v[2] - mu) * rs * g1v.z + b1v.z);
  w[3] = xv.w + ((v[3] - mu) * rs * g1v.w + b1v.w);
  s1 = w[0] + w[1] + w[2] + w[3];
  s2 = w[0]*w[0] + w[1]*w[1] + w[2]*w[2] + w[3]*w[3];
  block_sum2(s1, s2, red, t);
  mu = s1 * (1.f / 1024.f);
  rs = rsqrtf(s2 * (1.f / 1024.f) - mu * mu + 1e-5f);
  float4 g2v = *(const float4*)(g2 + t * 4);
  float4 b2v = *(const float4*)(b2 + t * 4);
  U4 ov;
  ov.s[0] = f2bf((w[0] - mu) * rs * g2v.x + b2v.x);
  ov.s[1] = f2bf((w[1] - mu) * rs * g2v.y + b2v.y);
  ov.s[2] = f2bf((w[2] - mu) * rs * g2v.z + b2v.z);
  ov.s[3] = f2bf((w[3] - mu) * rs * g2v.w + b2v.w);
  *(uint2*)(x1 + base) = ov.u;
}

__global__ __launch_bounds__(256) void ln2_k(const u16* __restrict__ y,
                                             const u16* __restrict__ x1,
                                             const float* __restrict__ g,
                                             const float* __restrict__ b,
                                             float* __restrict__ out) {
  __shared__ float red[8];
  int row = blockIdx.x, t = threadIdx.x;
  size_t base = (size_t)row * 1024 + t * 4;
  U4 yv; yv.u = *(const uint2*)(y + base);
  U4 xv; xv.u = *(const uint2*)(x1 + base);
  float w[4];
#pragma unroll
  for (int i = 0; i < 4; i++) w[i] = bf2f(yv.s[i]) + bf2f(xv.s[i]);
  float s1 = w[0] + w[1] + w[2] + w[3];
  float s2 = w[0]*w[0] + w[1]*w[1] + w[2]*w[2] + w[3]*w[3];
  block_sum2(s1, s2, red, t);
  float mu = s1 * (1.f / 1024.f);
  float rs = rsqrtf(s2 * (1.f / 1024.f) - mu * mu + 1e-5f);
  float4 gv = *(const float4*)(g + t * 4);
  float4 bv = *(const float4*)(b + t * 4);
  float4 ov;
  ov.x = (w[0] - mu) * rs * gv.x + bv.x;
  ov.y = (w[1] - mu) * rs * gv.y + bv.y;
  ov.z = (w[2] - mu) * rs * gv.z + bv.z;
  ov.w = (w[3] - mu) * rs * gv.w + bv.w;
  *(float4*)(out + base) = ov;
}

// ---------------------------------------------------------------------------
extern "C" void kernel_launch(void* const* d_in, const int* in_sizes, int n_in,
                              void* d_out, int out_size, void* d_ws, size_t ws_size,
                              hipStream_t stream) {
  (void)in_sizes; (void)n_in; (void)out_size; (void)ws_size;
  const float* x    = (const float*)d_in[0];
  const int*   mask = (const int*)d_in[1];
  const float* Wq = (const float*)d_in[2];  const float* bq = (const float*)d_in[3];
  const float* Wk = (const float*)d_in[4];  const float* bk = (const float*)d_in[5];
  const float* Wv = (const float*)d_in[6];  const float* bv = (const float*)d_in[7];
  const float* Wo = (const float*)d_in[8];  const float* bo = (const float*)d_in[9];
  const float* temp = (const float*)d_in[10];
  const float* tw   = (const float*)d_in[11];
  const float* gW   = (const float*)d_in[12]; const float* gb  = (const float*)d_in[13];
  const float* lag  = (const float*)d_in[14]; const float* lab = (const float*)d_in[15];
  const float* f1W  = (const float*)d_in[16]; const float* f1b = (const float*)d_in[17];
  const float* f2W  = (const float*)d_in[18]; const float* f2b = (const float*)d_in[19];
  const float* n1g  = (const float*)d_in[20]; const float* n1b = (const float*)d_in[21];
  const float* n2g  = (const float*)d_in[22]; const float* n2b = (const float*)d_in[23];
  float* out = (float*)d_out;

  // ws: 5 bf16 slots (40 MiB) + d_out as 2 bf16 slots (16 MiB).
  //  s0: WqT  -> VT      -> f1WT
  //  s1: WkT  -> maskbits-> f2WT
  //  s2: WvT  -> CT      -> Y
  //  s3: Q    -> X1
  //  s4: xb   -> WoT
  //  d0: K    -> PO      -> H(lower)
  //  d1: V    -> H(upper)   ... ln2 finally writes fp32 out over d0-d1
  u16* ws = (u16*)d_ws;
  const size_t MB4 = (size_t)4096 * 1024;
  u16* s0 = ws;
  u16* s1 = ws + 1 * MB4;
  u16* s2 = ws + 2 * MB4;
  u16* s3 = ws + 3 * MB4;
  u16* s4 = ws + 4 * MB4;
  u16* d0 = (u16*)d_out;
  u16* d1 = d0 + MB4;

  dim3 blk(256);
  cvt_k<<<dim3(4096), blk, 0, stream>>>(x, s4, 4096 * 1024);
  transpose_cvt3_k<<<dim3(16, 16, 3), blk, 0, stream>>>(Wq, Wk, Wv, s0, s1, s2);
  // fused QKV (M in x): Q->s3, K->d0, V->d1
  qkv_gemm<<<dim3(32, 8, 3), blk, 0, stream>>>(s4, s0, s1, s2, s3, d0, d1,
                                               bq, bk, bv, tw);
  // V -> VT (s0); mask -> bits (s1); WoT -> s4 (xb dead)
  vtrans_k<<<dim3(32, 32), blk, 0, stream>>>(d1, s0);
  mb_k<<<dim3(1024), blk, 0, stream>>>(mask, s1);
  transpose_cvt_k<<<dim3(16, 16), blk, 0, stream>>>(Wo, s4, 1024, 1024);
  // attention: ctx -> s2 (WvT dead)
  attn_k<<<dim3(1024), blk, 0, stream>>>(s3, d0, s0, s2, s1, gW, gb, temp);
  // Wo projection (BM=64, M in x): PO -> d0 (K dead)
  gemm_bt<64, 0, 1><<<dim3(64, 8), blk, 0, stream>>>(s2, s4, d0, bo, 4096, 1024, 1024);
  // LN(attn)+residual+LN: X1 -> s3 (Q dead)
  ln1_k<<<dim3(4096), blk, 0, stream>>>(d0, x, lag, lab, n1g, n1b, s3);
  // FFN: f1WT -> s0 (VT dead), f2WT -> s1 (bits dead), H -> d0-d1 (16 MiB)
  transpose_cvt_k<<<dim3(64, 16), blk, 0, stream>>>(f1W, s0, 1024, 4096);
  transpose_cvt_k<<<dim3(16, 64), blk, 0, stream>>>(f2W, s1, 4096, 1024);
  for (int i = 0; i < 2; i++) {
    const u16* Ai = s3 + (size_t)i * 2048 * 1024;
    u16* Yi = s2 + (size_t)i * 2048 * 1024;   // Y -> s2 (CT dead)
    gemm_bt<128, 2, 0><<<dim3(32, 16), blk, 0, stream>>>(Ai, s0, d0, f1b, 2048, 4096, 1024);
    gemm_bt<64, 0, 1><<<dim3(32, 8), blk, 0, stream>>>(d0, s1, Yi, f2b, 2048, 1024, 4096);
  }
  // final LN -> fp32 out (H dead)
  ln2_k<<<dim3(4096), blk, 0, stream>>>(s2, s3, n2g, n2b, out);
}

// Round 9
// 480.237 us; speedup vs baseline: 1.9601x; 1.2075x over previous
//
#include <hip/hip_runtime.h>
#include <stdint.h>
#include <math.h>

// ---------------------------------------------------------------------------
// EncoderLayer. I/O fp32 (mask int32). Internal bf16 MFMA, fp32 accum.
// R9: attn softmax de-chained (deferred l-reduction, no Ps barrier, uniform
// mask fast path, exp2 intrinsic, cheap P pack, bits prefetch). FFN full-size
// dispatches when ws_size >= 72 MiB (guarded, fallback = R8 halves path).
// ---------------------------------------------------------------------------

typedef uint16_t u16;
typedef unsigned long long u64;
typedef __attribute__((ext_vector_type(8))) short short8;   // 8 x bf16
typedef __attribute__((ext_vector_type(4))) float f32x4;

#define S_LEN 2048
#define DM 1024

#define GLOAD_LDS16(g, l)                                                      \
  __builtin_amdgcn_global_load_lds(                                            \
      (const __attribute__((address_space(1))) void*)(g),                      \
      (__attribute__((address_space(3))) void*)(l), 16, 0, 0)

__device__ __forceinline__ float bf2f(u16 h) {
  union { uint32_t u; float f; } x;
  x.u = ((uint32_t)h) << 16;
  return x.f;
}
__device__ __forceinline__ u16 f2bf(float f) {
  union { float f; uint32_t u; } x;
  x.f = f;
  uint32_t r = (x.u + 0x7fffu + ((x.u >> 16) & 1u)) >> 16;  // RNE
  return (u16)r;
}
__device__ __forceinline__ u16 f2bf_fast(float f) {  // round-half-up (2 ops)
  union { float f; uint32_t u; } x;
  x.f = f;
  return (u16)((x.u + 0x8000u) >> 16);
}

union U8 { uint4 u; u16 s[8]; };
union U4 { uint2 u; u16 s[4]; };

// ---------------------------------------------------------------------------
// fp32 -> bf16 elementwise
// ---------------------------------------------------------------------------
__global__ __launch_bounds__(256) void cvt_k(const float* __restrict__ in,
                                             u16* __restrict__ out, int n) {
  int i = (blockIdx.x * 256 + threadIdx.x) * 4;
  if (i >= n) return;
  float4 v = *(const float4*)(in + i);
  U4 o;
  o.s[0] = f2bf(v.x); o.s[1] = f2bf(v.y); o.s[2] = f2bf(v.z); o.s[3] = f2bf(v.w);
  *(uint2*)(out + i) = o.u;
}

// ---------------------------------------------------------------------------
// mask int32 [2048,2048] -> bitpacked u16 [2048,128] (bit j = mask!=0)
// ---------------------------------------------------------------------------
__global__ __launch_bounds__(256) void mb_k(const int* __restrict__ mask,
                                            u16* __restrict__ mb) {
  int tid = blockIdx.x * 256 + threadIdx.x;
  const int* src = mask + (size_t)tid * 16;
  uint32_t b = 0;
#pragma unroll
  for (int q = 0; q < 4; q++) {
    int4 m = *(const int4*)(src + q * 4);
    b |= (m.x != 0 ? 1u : 0u) << (q * 4 + 0);
    b |= (m.y != 0 ? 1u : 0u) << (q * 4 + 1);
    b |= (m.z != 0 ? 1u : 0u) << (q * 4 + 2);
    b |= (m.w != 0 ? 1u : 0u) << (q * 4 + 3);
  }
  mb[tid] = (u16)b;
}

// ---------------------------------------------------------------------------
// Weight convert+transpose: fp32 [R,C] -> bf16 [C,R]. grid(C/64,R/64)
// ---------------------------------------------------------------------------
__device__ __forceinline__ void tcvt_body(const float* __restrict__ in,
                                          u16* __restrict__ out, int R, int C) {
  __shared__ u16 tile[64][72];
  int c0 = blockIdx.x * 64, r0 = blockIdx.y * 64;
  int t = threadIdx.x;
  int r = t & 63, seg = t >> 6;
  const float* src = in + (size_t)(r0 + r) * C + c0 + seg * 16;
#pragma unroll
  for (int q = 0; q < 4; q++) {
    float4 v = *(const float4*)(src + q * 4);
    tile[r][seg * 16 + q * 4 + 0] = f2bf(v.x);
    tile[r][seg * 16 + q * 4 + 1] = f2bf(v.y);
    tile[r][seg * 16 + q * 4 + 2] = f2bf(v.z);
    tile[r][seg * 16 + q * 4 + 3] = f2bf(v.w);
  }
  __syncthreads();
  U8 v0, v1;
#pragma unroll
  for (int i = 0; i < 8; i++) v0.s[i] = tile[seg * 16 + i][r];
#pragma unroll
  for (int i = 0; i < 8; i++) v1.s[i] = tile[seg * 16 + 8 + i][r];
  u16* dst = out + (size_t)(c0 + r) * R + r0 + seg * 16;
  *(uint4*)dst = v0.u;
  *(uint4*)(dst + 8) = v1.u;
}

__global__ __launch_bounds__(256) void transpose_cvt_k(const float* __restrict__ in,
                                                       u16* __restrict__ out,
                                                       int R, int C) {
  tcvt_body(in, out, R, C);
}

__global__ __launch_bounds__(256) void transpose_cvt3_k(const float* __restrict__ i0,
                                                        const float* __restrict__ i1,
                                                        const float* __restrict__ i2,
                                                        u16* __restrict__ o0,
                                                        u16* __restrict__ o1,
                                                        u16* __restrict__ o2) {
  int z = blockIdx.z;
  const float* in = (z == 0) ? i0 : (z == 1) ? i1 : i2;
  u16* out = (z == 0) ? o0 : (z == 1) ? o1 : o2;
  tcvt_body(in, out, 1024, 1024);
}

// ---------------------------------------------------------------------------
// V [2*2048,1024] bf16 -> VT [(b*16+h)*64 + d][2048] bf16. grid(32 ktile, 32 bh)
// ---------------------------------------------------------------------------
__global__ __launch_bounds__(256) void vtrans_k(const u16* __restrict__ V,
                                                u16* __restrict__ VT) {
  __shared__ u16 tile[64][72];
  int bx = blockIdx.x, bh = blockIdx.y;
  int b = bh >> 4, h = bh & 15;
  int t = threadIdx.x, r = t & 63, seg = t >> 6;
  const u16* src = V + (size_t)(b * S_LEN + bx * 64 + r) * DM + h * 64 + seg * 16;
  *(uint4*)&tile[r][seg * 16] = *(const uint4*)src;
  *(uint4*)&tile[r][seg * 16 + 8] = *(const uint4*)(src + 8);
  __syncthreads();
  U8 v0, v1;
#pragma unroll
  for (int i = 0; i < 8; i++) v0.s[i] = tile[seg * 16 + i][r];
#pragma unroll
  for (int i = 0; i < 8; i++) v1.s[i] = tile[seg * 16 + 8 + i][r];
  u16* dst = VT + ((size_t)bh * 64 + r) * S_LEN + bx * 64 + seg * 16;
  *(uint4*)dst = v0.u;
  *(uint4*)(dst + 8) = v1.u;
}

// ---------------------------------------------------------------------------
// bf16 GEMM: C[M,N] = A[M,K] @ Bt[N,K]^T. Tile BM x 128, BK=32, 4 waves.
// BM in {128, 64}. EPI: 0=+bias ; 2=+bias then exact GELU.
// MXS=1: M-tile is blockIdx.x.
// ---------------------------------------------------------------------------
template <int BM, int EPI, int MXS>
__global__ __launch_bounds__(256) void gemm_bt(const u16* __restrict__ A,
                                               const u16* __restrict__ Bt,
                                               u16* __restrict__ C,
                                               const float* __restrict__ bias,
                                               int M, int N, int K) {
  constexpr int MI = BM / 32;
  constexpr int RPW = BM / 4;
  __shared__ u16 As[BM * 32];
  __shared__ u16 Bs[128 * 32];
  int t = threadIdx.x;
  int wid = t >> 6, lane = t & 63;
  int g = lane >> 4, li = lane & 15;
  int bx = MXS ? blockIdx.y : blockIdx.x;
  int by = MXS ? blockIdx.x : blockIdx.y;
  int wr = (wid >> 1) * (BM / 2), wc = (wid & 1) * 64;

  const u16* a0 = A + (size_t)(by * BM + wid * RPW + (lane >> 2)) * K + (lane & 3) * 8;
  const u16* b0 = Bt + (size_t)(bx * 128 + wid * 32 + (lane >> 2)) * K + (lane & 3) * 8;
  u16* lA0 = &As[wid * RPW * 32];
  u16* lB0 = &Bs[wid * 1024];

  f32x4 acc[MI][4];
#pragma unroll
  for (int i = 0; i < MI; i++)
#pragma unroll
    for (int j = 0; j < 4; j++) acc[i][j] = (f32x4){0.f, 0.f, 0.f, 0.f};

  for (int k0 = 0; k0 < K; k0 += 32) {
    GLOAD_LDS16(a0 + k0, lA0);
    if (BM == 128) GLOAD_LDS16(a0 + (size_t)16 * K + k0, lA0 + 512);
    GLOAD_LDS16(b0 + k0, lB0);
    GLOAD_LDS16(b0 + (size_t)16 * K + k0, lB0 + 512);
    __syncthreads();
    short8 af[MI], bfv[4];
#pragma unroll
    for (int i = 0; i < MI; i++)
      af[i] = *(const short8*)&As[(wr + i * 16 + li) * 32 + g * 8];
#pragma unroll
    for (int i = 0; i < 4; i++)
      bfv[i] = *(const short8*)&Bs[(wc + i * 16 + li) * 32 + g * 8];
#pragma unroll
    for (int mi = 0; mi < MI; mi++)
#pragma unroll
      for (int ni = 0; ni < 4; ni++)
        acc[mi][ni] = __builtin_amdgcn_mfma_f32_16x16x32_bf16(
            af[mi], bfv[ni], acc[mi][ni], 0, 0, 0);
    __syncthreads();
  }

#pragma unroll
  for (int ni = 0; ni < 4; ni++) {
    int col = bx * 128 + wc + ni * 16 + li;
    float bv = bias[col];
#pragma unroll
    for (int mi = 0; mi < MI; mi++) {
#pragma unroll
      for (int r = 0; r < 4; r++) {
        int row = by * BM + wr + mi * 16 + g * 4 + r;
        float v = acc[mi][ni][r] + bv;
        if (EPI == 2) v = 0.5f * v * (1.0f + erff(v * 0.70710678118654752f));
        C[(size_t)row * N + col] = f2bf(v);
      }
    }
  }
}

// ---------------------------------------------------------------------------
// Fused QKV projection: grid (32, 8, 3); x=M-tile, y=N-tile, z=weight.
// ---------------------------------------------------------------------------
__global__ __launch_bounds__(256) void qkv_gemm(const u16* __restrict__ A,
                                                const u16* __restrict__ WTq,
                                                const u16* __restrict__ WTk,
                                                const u16* __restrict__ WTv,
                                                u16* __restrict__ Cq,
                                                u16* __restrict__ Ck,
                                                u16* __restrict__ Cv,
                                                const float* __restrict__ bq,
                                                const float* __restrict__ bk,
                                                const float* __restrict__ bv,
                                                const float* __restrict__ tw) {
  const int K = 1024, N = 1024;
  __shared__ u16 As[128 * 32];
  __shared__ u16 Bs[128 * 32];
  int t = threadIdx.x;
  int wid = t >> 6, lane = t & 63;
  int g = lane >> 4, li = lane & 15;
  int by = blockIdx.x, bx = blockIdx.y, z = blockIdx.z;
  int wr = (wid >> 1) * 64, wc = (wid & 1) * 64;

  const u16* Bt = (z == 0) ? WTq : (z == 1) ? WTk : WTv;
  u16* C = (z == 0) ? Cq : (z == 1) ? Ck : Cv;
  const float* bias = (z == 0) ? bq : (z == 1) ? bk : bv;

  const u16* a0 = A + (size_t)(by * 128 + wid * 32 + (lane >> 2)) * K + (lane & 3) * 8;
  const u16* b0 = Bt + (size_t)(bx * 128 + wid * 32 + (lane >> 2)) * K + (lane & 3) * 8;
  u16* lA0 = &As[wid * 1024];
  u16* lB0 = &Bs[wid * 1024];

  f32x4 acc[4][4];
#pragma unroll
  for (int i = 0; i < 4; i++)
#pragma unroll
    for (int j = 0; j < 4; j++) acc[i][j] = (f32x4){0.f, 0.f, 0.f, 0.f};

  for (int k0 = 0; k0 < K; k0 += 32) {
    GLOAD_LDS16(a0 + k0, lA0);
    GLOAD_LDS16(a0 + (size_t)16 * K + k0, lA0 + 512);
    GLOAD_LDS16(b0 + k0, lB0);
    GLOAD_LDS16(b0 + (size_t)16 * K + k0, lB0 + 512);
    __syncthreads();
    short8 af[4], bfv[4];
#pragma unroll
    for (int i = 0; i < 4; i++)
      af[i] = *(const short8*)&As[(wr + i * 16 + li) * 32 + g * 8];
#pragma unroll
    for (int i = 0; i < 4; i++)
      bfv[i] = *(const short8*)&Bs[(wc + i * 16 + li) * 32 + g * 8];
#pragma unroll
    for (int mi = 0; mi < 4; mi++)
#pragma unroll
      for (int ni = 0; ni < 4; ni++)
        acc[mi][ni] = __builtin_amdgcn_mfma_f32_16x16x32_bf16(
            af[mi], bfv[ni], acc[mi][ni], 0, 0, 0);
    __syncthreads();
  }

#pragma unroll
  for (int ni = 0; ni < 4; ni++) {
    int col = bx * 128 + wc + ni * 16 + li;
    float bvv = bias[col];
    if (z == 0) bvv += tw[col];
#pragma unroll
    for (int mi = 0; mi < 4; mi++) {
#pragma unroll
      for (int r = 0; r < 4; r++) {
        int row = by * 128 + wr + mi * 16 + g * 4 + r;
        C[(size_t)row * N + col] = f2bf(acc[mi][ni][r] + bvv);
      }
    }
  }
}

// ---------------------------------------------------------------------------
// Flash attention. grid 1024, 256 thr. bh in low 5 bits (XCD locality).
// exp2-domain softmax; l-reduction deferred to epilogue; Ps is wave-private
// (no block barrier; wave_barrier pins compiler order).
// ---------------------------------------------------------------------------
__global__ __launch_bounds__(256) void attn_k(const u16* __restrict__ Q,
                                              const u16* __restrict__ Kp,
                                              const u16* __restrict__ VT,
                                              u16* __restrict__ CTX,
                                              const u16* __restrict__ mb,
                                              const float* __restrict__ gateW,
                                              const float* __restrict__ gateb,
                                              const float* __restrict__ temp) {
  __shared__ u16 Qs[64][72];
  __shared__ u16 Ks[64][72];      // K tile: [kpos][d]
  __shared__ u16 Vs[64][72];      // V^T tile: [d][kpos]
  __shared__ u16 Ps[4][16][72];   // per-wave P bounce
  __shared__ float gate_s[64];

  int blk = blockIdx.x;
  int bh = blk & 31, qt = blk >> 5;
  int b = bh >> 4, h = bh & 15;
  int t = threadIdx.x, wid = t >> 6, lane = t & 63;
  int g = lane >> 4, li = lane & 15;
  int sq0 = qt * 64;

  const u16* Qb  = Q + ((size_t)b * S_LEN) * DM + h * 64;
  const u16* Kb  = Kp + ((size_t)b * S_LEN) * DM + h * 64;
  const u16* VTb = VT + ((size_t)(b * 16 + h) * 64) * S_LEN;

  {
    int r = t >> 2, cs = (t & 3) * 16;
    const u16* src = Qb + (size_t)(sq0 + r) * DM + cs;
    *(uint4*)&Qs[r][cs] = *(const uint4*)src;
    *(uint4*)&Qs[r][cs + 8] = *(const uint4*)(src + 8);
  }
  __syncthreads();
  if (t < 64) {
    float acc = gateb[0];
#pragma unroll
    for (int d = 0; d < 64; d++) acc += bf2f(Qs[t][d]) * gateW[d];
    gate_s[t] = 1.f / (1.f + __expf(-acc));
  }
  __syncthreads();

  const float LOG2E = 1.4426950408889634f;
  float invt2 = LOG2E / temp[0];
  const float NEG2 = -1.0e9f * 1.4426950408889634f;
  short8 qf0 = *(const short8*)&Qs[wid * 16 + li][g * 8];
  short8 qf1 = *(const short8*)&Qs[wid * 16 + li][32 + g * 8];
  float gqs[4], ng[4];  // gate*scale (exp2 domain), masked-out value
  int sq[4];
#pragma unroll
  for (int r = 0; r < 4; r++) {
    float gq = gate_s[wid * 16 + g * 4 + r];
    gqs[r] = gq * invt2;
    ng[r] = NEG2 * gq;
    sq[r] = sq0 + wid * 16 + g * 4 + r;
  }

  float m_i[4], psl[4];
  f32x4 o[4];
#pragma unroll
  for (int r = 0; r < 4; r++) { m_i[r] = -1e30f; psl[r] = 0.f; }
#pragma unroll
  for (int n = 0; n < 4; n++) o[n] = (f32x4){0.f, 0.f, 0.f, 0.f};

  for (int kt = 0; kt < 32; kt++) {
    __syncthreads();   // protect Ks/Vs overwrite vs previous-iter reads
    {
      int r = t >> 2, cs = (t & 3) * 16;
      const u16* srcK = Kb + (size_t)(kt * 64 + r) * DM + cs;
      *(uint4*)&Ks[r][cs] = *(const uint4*)srcK;
      *(uint4*)&Ks[r][cs + 8] = *(const uint4*)(srcK + 8);
      const u16* srcV = VTb + (size_t)r * S_LEN + kt * 64 + cs;
      *(uint4*)&Vs[r][cs] = *(const uint4*)srcV;
      *(uint4*)&Vs[r][cs + 8] = *(const uint4*)(srcV + 8);
    }
    // prefetch mask bits while staging completes
    u64 bits[4];
#pragma unroll
    for (int r = 0; r < 4; r++)
      bits[r] = *(const u64*)(mb + (size_t)sq[r] * 128 + kt * 4);
    __syncthreads();

    // S = Q K^T
    f32x4 sc[4];
#pragma unroll
    for (int ni = 0; ni < 4; ni++) {
      sc[ni] = (f32x4){0.f, 0.f, 0.f, 0.f};
      short8 kf0 = *(const short8*)&Ks[ni * 16 + li][g * 8];
      short8 kf1 = *(const short8*)&Ks[ni * 16 + li][32 + g * 8];
      sc[ni] = __builtin_amdgcn_mfma_f32_16x16x32_bf16(qf0, kf0, sc[ni], 0, 0, 0);
      sc[ni] = __builtin_amdgcn_mfma_f32_16x16x32_bf16(qf1, kf1, sc[ni], 0, 0, 0);
    }

    float sval[4][4];
    float rmax[4] = {-1e30f, -1e30f, -1e30f, -1e30f};
    bool allm = ((bits[0] & bits[1] & bits[2] & bits[3]) == ~0ull);
    if (__all(allm)) {   // wave-uniform fast path (no masked elements)
#pragma unroll
      for (int ni = 0; ni < 4; ni++)
#pragma unroll
        for (int r = 0; r < 4; r++) {
          float s = sc[ni][r] * gqs[r];
          sval[ni][r] = s;
          rmax[r] = fmaxf(rmax[r], s);
        }
    } else {
      u64 bs[4];
#pragma unroll
      for (int r = 0; r < 4; r++) bs[r] = bits[r] >> li;
#pragma unroll
      for (int ni = 0; ni < 4; ni++)
#pragma unroll
        for (int r = 0; r < 4; r++) {
          float s = ((bs[r] >> (ni * 16)) & 1ull) ? sc[ni][r] * gqs[r] : ng[r];
          sval[ni][r] = s;
          rmax[r] = fmaxf(rmax[r], s);
        }
    }
#pragma unroll
    for (int off = 1; off < 16; off <<= 1)
#pragma unroll
      for (int r = 0; r < 4; r++)
        rmax[r] = fmaxf(rmax[r], __shfl_xor(rmax[r], off, 64));

    float alpha[4];
#pragma unroll
    for (int r = 0; r < 4; r++) {
      float mnew = fmaxf(m_i[r], rmax[r]);
      alpha[r] = __builtin_amdgcn_exp2f(m_i[r] - mnew);
      m_i[r] = mnew;
    }
    float pp[4] = {0.f, 0.f, 0.f, 0.f};
#pragma unroll
    for (int ni = 0; ni < 4; ni++)
#pragma unroll
      for (int r = 0; r < 4; r++) {
        float p = __builtin_amdgcn_exp2f(sval[ni][r] - m_i[r]);
        pp[r] += p;
        Ps[wid][g * 4 + r][ni * 16 + li] = f2bf_fast(p);
      }
#pragma unroll
    for (int r = 0; r < 4; r++) psl[r] = psl[r] * alpha[r] + pp[r];
#pragma unroll
    for (int n = 0; n < 4; n++)
#pragma unroll
      for (int r = 0; r < 4; r++) o[n][r] *= alpha[r];

    __builtin_amdgcn_wave_barrier();  // Ps is wave-private: pin order, no s_barrier

    short8 pf0 = *(const short8*)&Ps[wid][li][g * 8];
    short8 pf1 = *(const short8*)&Ps[wid][li][32 + g * 8];
#pragma unroll
    for (int ni = 0; ni < 4; ni++) {
      short8 vf0 = *(const short8*)&Vs[ni * 16 + li][g * 8];
      short8 vf1 = *(const short8*)&Vs[ni * 16 + li][32 + g * 8];
      o[ni] = __builtin_amdgcn_mfma_f32_16x16x32_bf16(pf0, vf0, o[ni], 0, 0, 0);
      o[ni] = __builtin_amdgcn_mfma_f32_16x16x32_bf16(pf1, vf1, o[ni], 0, 0, 0);
    }
  }

  // deferred l reduction: sum psl over the 16 lanes sharing each row group
  float linv[4];
#pragma unroll
  for (int r = 0; r < 4; r++) {
    float l = psl[r];
#pragma unroll
    for (int off = 1; off < 16; off <<= 1) l += __shfl_xor(l, off, 64);
    linv[r] = 1.f / l;
  }
#pragma unroll
  for (int ni = 0; ni < 4; ni++) {
    int col = h * 64 + ni * 16 + li;
#pragma unroll
    for (int r = 0; r < 4; r++) {
      size_t row = (size_t)b * S_LEN + sq[r];
      CTX[row * DM + col] = f2bf(o[ni][r] * linv[r]);
    }
  }
}

// ---------------------------------------------------------------------------
// LayerNorm kernels. One block per row.
// ---------------------------------------------------------------------------
__device__ __forceinline__ void block_sum2(float& a, float& b, float* red, int t) {
#pragma unroll
  for (int off = 32; off > 0; off >>= 1) {
    a += __shfl_xor(a, off, 64);
    b += __shfl_xor(b, off, 64);
  }
  __syncthreads();
  if ((t & 63) == 0) {
    red[(t >> 6) * 2] = a;
    red[(t >> 6) * 2 + 1] = b;
  }
  __syncthreads();
  a = red[0] + red[2] + red[4] + red[6];
  b = red[1] + red[3] + red[5] + red[7];
}

__global__ __launch_bounds__(256) void ln1_k(const u16* __restrict__ po,
                                             const float* __restrict__ x,
                                             const float* __restrict__ g1,
                                             const float* __restrict__ b1,
                                             const float* __restrict__ g2,
                                             const float* __restrict__ b2,
                                             u16* __restrict__ x1) {
  __shared__ float red[8];
  int row = blockIdx.x, t = threadIdx.x;
  size_t base = (size_t)row * 1024 + t * 4;
  U4 pv; pv.u = *(const uint2*)(po + base);
  float v[4];
#pragma unroll
  for (int i = 0; i < 4; i++) v[i] = bf2f(pv.s[i]);
  float s1 = v[0] + v[1] + v[2] + v[3];
  float s2 = v[0]*v[0] + v[1]*v[1] + v[2]*v[2] + v[3]*v[3];
  block_sum2(s1, s2, red, t);
  float mu = s1 * (1.f / 1024.f);
  float rs = rsqrtf(s2 * (1.f / 1024.f) - mu * mu + 1e-5f);
  float4 xv = *(const float4*)(x + base);
  float4 g1v = *(const float4*)(g1 + t * 4);
  float4 b1v = *(const float4*)(b1 + t * 4);
  float w[4];
  w[0] = xv.x + ((v[0] - mu) * rs * g1v.x + b1v.x);
  w[1] = xv.y + ((v[1] - mu) * rs * g1v.y + b1v.y);
  w[2] = xv.z + ((v[2] - mu) * rs * g1v.z + b1v.z);
  w[3] = xv.w + ((v[3] - mu) * rs * g1v.w + b1v.w);
  s1 = w[0] + w[1] + w[2] + w[3];
  s2 = w[0]*w[0] + w[1]*w[1] + w[2]*w[2] + w[3]*w[3];
  block_sum2(s1, s2, red, t);
  mu = s1 * (1.f / 1024.f);
  rs = rsqrtf(s2 * (1.f / 1024.f) - mu * mu + 1e-5f);
  float4 g2v = *(const float4*)(g2 + t * 4);
  float4 b2v = *(const float4*)(b2 + t * 4);
  U4 ov;
  ov.s[0] = f2bf((w[0] - mu) * rs * g2v.x + b2v.x);
  ov.s[1] = f2bf((w[1] - mu) * rs * g2v.y + b2v.y);
  ov.s[2] = f2bf((w[2] - mu) * rs * g2v.z + b2v.z);
  ov.s[3] = f2bf((w[3] - mu) * rs * g2v.w + b2v.w);
  *(uint2*)(x1 + base) = ov.u;
}

__global__ __launch_bounds__(256) void ln2_k(const u16* __restrict__ y,
                                             const u16* __restrict__ x1,
                                             const float* __restrict__ g,
                                             const float* __restrict__ b,
                                             float* __restrict__ out) {
  __shared__ float red[8];
  int row = blockIdx.x, t = threadIdx.x;
  size_t base = (size_t)row * 1024 + t * 4;
  U4 yv; yv.u = *(const uint2*)(y + base);
  U4 xv; xv.u = *(const uint2*)(x1 + base);
  float w[4];
#pragma unroll
  for (int i = 0; i < 4; i++) w[i] = bf2f(yv.s[i]) + bf2f(xv.s[i]);
  float s1 = w[0] + w[1] + w[2] + w[3];
  float s2 = w[0]*w[0] + w[1]*w[1] + w[2]*w[2] + w[3]*w[3];
  block_sum2(s1, s2, red, t);
  float mu = s1 * (1.f / 1024.f);
  float rs = rsqrtf(s2 * (1.f / 1024.f) - mu * mu + 1e-5f);
  float4 gv = *(const float4*)(g + t * 4);
  float4 bv = *(const float4*)(b + t * 4);
  float4 ov;
  ov.x = (w[0] - mu) * rs * gv.x + bv.x;
  ov.y = (w[1] - mu) * rs * gv.y + bv.y;
  ov.z = (w[2] - mu) * rs * gv.z + bv.z;
  ov.w = (w[3] - mu) * rs * gv.w + bv.w;
  *(float4*)(out + base) = ov;
}

// ---------------------------------------------------------------------------
extern "C" void kernel_launch(void* const* d_in, const int* in_sizes, int n_in,
                              void* d_out, int out_size, void* d_ws, size_t ws_size,
                              hipStream_t stream) {
  (void)in_sizes; (void)n_in; (void)out_size;
  const float* x    = (const float*)d_in[0];
  const int*   mask = (const int*)d_in[1];
  const float* Wq = (const float*)d_in[2];  const float* bq = (const float*)d_in[3];
  const float* Wk = (const float*)d_in[4];  const float* bk = (const float*)d_in[5];
  const float* Wv = (const float*)d_in[6];  const float* bv = (const float*)d_in[7];
  const float* Wo = (const float*)d_in[8];  const float* bo = (const float*)d_in[9];
  const float* temp = (const float*)d_in[10];
  const float* tw   = (const float*)d_in[11];
  const float* gW   = (const float*)d_in[12]; const float* gb  = (const float*)d_in[13];
  const float* lag  = (const float*)d_in[14]; const float* lab = (const float*)d_in[15];
  const float* f1W  = (const float*)d_in[16]; const float* f1b = (const float*)d_in[17];
  const float* f2W  = (const float*)d_in[18]; const float* f2b = (const float*)d_in[19];
  const float* n1g  = (const float*)d_in[20]; const float* n1b = (const float*)d_in[21];
  const float* n2g  = (const float*)d_in[22]; const float* n2b = (const float*)d_in[23];
  float* out = (float*)d_out;

  u16* ws = (u16*)d_ws;
  const size_t MB4 = (size_t)4096 * 1024;
  u16* s0 = ws;                 // WqT  -> VT       -> f1WT
  u16* s1 = ws + 1 * MB4;       // WkT  -> maskbits -> f2WT
  u16* s2 = ws + 2 * MB4;       // WvT  -> CT       -> Y
  u16* s3 = ws + 3 * MB4;       // Q    -> X1
  u16* s4 = ws + 4 * MB4;       // xb   -> WoT
  u16* d0 = (u16*)d_out;        // K    -> PO       -> H(lo, small-ws path)
  u16* d1 = d0 + MB4;           // V    -> H(hi, small-ws path)
  bool bigws = ws_size >= (size_t)9 * 8 * 1024 * 1024;  // 72 MiB
  u16* Hfull = ws + 5 * MB4;    // 32 MiB contiguous (bigws path)

  dim3 blk(256);
  cvt_k<<<dim3(4096), blk, 0, stream>>>(x, s4, 4096 * 1024);
  transpose_cvt3_k<<<dim3(16, 16, 3), blk, 0, stream>>>(Wq, Wk, Wv, s0, s1, s2);
  qkv_gemm<<<dim3(32, 8, 3), blk, 0, stream>>>(s4, s0, s1, s2, s3, d0, d1,
                                               bq, bk, bv, tw);
  vtrans_k<<<dim3(32, 32), blk, 0, stream>>>(d1, s0);
  mb_k<<<dim3(1024), blk, 0, stream>>>(mask, s1);
  transpose_cvt_k<<<dim3(16, 16), blk, 0, stream>>>(Wo, s4, 1024, 1024);
  attn_k<<<dim3(1024), blk, 0, stream>>>(s3, d0, s0, s2, s1, gW, gb, temp);
  gemm_bt<64, 0, 1><<<dim3(64, 8), blk, 0, stream>>>(s2, s4, d0, bo, 4096, 1024, 1024);
  ln1_k<<<dim3(4096), blk, 0, stream>>>(d0, x, lag, lab, n1g, n1b, s3);
  transpose_cvt_k<<<dim3(64, 16), blk, 0, stream>>>(f1W, s0, 1024, 4096);
  transpose_cvt_k<<<dim3(16, 64), blk, 0, stream>>>(f2W, s1, 4096, 1024);
  if (bigws) {
    // full-size FFN: fc1 1024 blocks, fc2 512 blocks (B-tile resident per XCD)
    gemm_bt<128, 2, 0><<<dim3(32, 32), blk, 0, stream>>>(s3, s0, Hfull, f1b,
                                                         4096, 4096, 1024);
    gemm_bt<64, 0, 0><<<dim3(8, 64), blk, 0, stream>>>(Hfull, s1, s2, f2b,
                                                       4096, 1024, 4096);
  } else {
    for (int i = 0; i < 2; i++) {
      const u16* Ai = s3 + (size_t)i * 2048 * 1024;
      u16* Yi = s2 + (size_t)i * 2048 * 1024;
      gemm_bt<128, 2, 0><<<dim3(32, 16), blk, 0, stream>>>(Ai, s0, d0, f1b,
                                                           2048, 4096, 1024);
      gemm_bt<64, 0, 1><<<dim3(32, 8), blk, 0, stream>>>(d0, s1, Yi, f2b,
                                                         2048, 1024, 4096);
    }
  }
  ln2_k<<<dim3(4096), blk, 0, stream>>>(s2, s3, n2g, n2b, out);
}